// Round 6
// baseline (465.464 us; speedup 1.0000x reference)
//
#include <hip/hip_runtime.h>
#include <hip/hip_bf16.h>
#include <stdint.h>

#define NB 4096
#define NC 100
#define NROWS (NB*NC)        // 409600
#define NTILES (NROWS/64)    // 6400
#define GRID_F 768
#define LH 200
#define LW 50

typedef short v8s __attribute__((ext_vector_type(8)));
typedef float v4f __attribute__((ext_vector_type(4)));
typedef float v2f __attribute__((ext_vector_type(2)));

__device__ __forceinline__ v4f mfma16(v8s a, v8s b, v4f c) {
  return __builtin_amdgcn_mfma_f32_16x16x32_bf16(a, b, c, 0, 0, 0);
}

// packed f32x2 -> bf16x2 (lo = first arg), RNE
__device__ __forceinline__ uint32_t pkbf(float lo, float hi) {
  uint32_t r;
  asm("v_cvt_pk_bf16_f32 %0, %1, %2" : "=v"(r) : "v"(lo), "v"(hi));
  return r;
}

__device__ __forceinline__ uint16_t bf16r(float f) {
  uint32_t u = __builtin_bit_cast(uint32_t, f);
  u = (u + 0x7fffu + ((u >> 16) & 1u)) >> 16;
  return (uint16_t)u;
}

__device__ __forceinline__ float flo(uint32_t u) { return __builtin_bit_cast(float, u << 16); }
__device__ __forceinline__ float fhi(uint32_t u) { return __builtin_bit_cast(float, u & 0xffff0000u); }

__device__ __forceinline__ int ntli(const int* p) { return __builtin_nontemporal_load(p); }
__device__ __forceinline__ float ntlf(const float* p) { return __builtin_nontemporal_load(p); }

// barrier that does NOT drain vmcnt: LDS-safe (lgkmcnt), global loads stay in flight
__device__ __forceinline__ void barx() {
  asm volatile("s_waitcnt lgkmcnt(0)" ::: "memory");
  __builtin_amdgcn_s_barrier();
  asm volatile("" ::: "memory");
}

// ---------------- workspace layout ----------------
// [0,512K) uv f32 | [512K,641K) frags | [640K,...) bf16 tables (greedy)
#define OFF_UV 0
#define OFF_FW 524288
#define OFF_TB 655360
#define ET_BYTES (34253*64)
#define EC_BYTES (10001*64)
#define EA_BYTES (5001*64)
#define EL_BYTES (28*64)
#define WS_ALL4 (OFF_TB + ET_BYTES + EC_BYTES + EA_BYTES + EL_BYTES)  // 3,809,472
#define WS_CAL  (OFF_TB + EC_BYTES + EA_BYTES + EL_BYTES)             // 1,617,280
#define WS_AL   (OFF_TB + EA_BYTES + EL_BYTES)                        //   977,216

#define FRAG_B1 0     // 2 frags (even/odd output cols)
#define FRAG_T0 2     // 32 frags: g = wv*8 + ch*4 + ks*2 + p   (k identity)
#define FRAG_T1 34    // 64 frags: g = wv*16 + ch*8 + ks*2 + p  (k PERM32-paired)
#define FRAG_T2 98    // 16 frags: g = gcol*4 + ks              (k PERM32-paired, n=gcol*16+lr)
#define NFRAGS 114

// ---------------- f32 -> bf16 table convert ----------------
__global__ void k_cvt1(const float* __restrict__ src, uint32_t* __restrict__ dst, int n8) {
  int i = blockIdx.x * 256 + threadIdx.x;
  if (i >= n8) return;
  const float* p = src + (size_t)i * 8;
  float4 a = *(const float4*)p;
  float4 b = *(const float4*)(p + 4);
  uint32_t* d = dst + (size_t)i * 4;
  d[0] = pkbf(a.x, a.y); d[1] = pkbf(a.z, a.w);
  d[2] = pkbf(b.x, b.y); d[3] = pkbf(b.z, b.w);
}

// ---------------- build weight B-fragments ----------------
__global__ void k_prep(const float* __restrict__ Wb1, const float* __restrict__ Wt0,
                       const float* __restrict__ Wt1, const float* __restrict__ Wt2,
                       uint16_t* __restrict__ fb) {
  int f = blockIdx.x;
  int t = threadIdx.x;
  uint16_t res[2];
  #pragma unroll
  for (int e2 = 0; e2 < 2; ++e2) {
    int e = t * 2 + e2;        // 0..511
    int l = e >> 3, i = e & 7;
    int lr = l & 15, lg = l >> 4;
    float v;
    if (f < FRAG_T0) {                       // Wb1: frag f holds output cols 2*lr+f
      v = Wb1[(lg * 8 + i) * 32 + 2 * lr + f];
    } else if (f < FRAG_T1) {                // Wt0 (k identity)
      int g = f - FRAG_T0;
      int wv = g >> 3, ch = (g >> 2) & 1, ks = (g >> 1) & 1, p = g & 1;
      int n = ch * 128 + wv * 32 + p * 16 + lr;
      int kl = ks * 32 + lg * 8 + i;
      v = Wt0[kl * 256 + n];
    } else if (f < FRAG_T2) {                // Wt1 (act1 pkbf-paired)
      int g = f - FRAG_T1;
      int wv = g >> 4, ch = (g >> 3) & 1, ks = (g >> 1) & 3, p = g & 1;
      int n = wv * 32 + p * 16 + lr;
      int kl = ks * 32 + lg * 8 + i;
      int ok = ch * 128 + (kl & ~31) + ((kl & 31) >> 1) + ((kl & 1) << 4);
      v = Wt1[ok * 128 + n];
    } else {                                 // Wt2 (act2 pkbf-paired)
      int g = f - FRAG_T2;
      int gc = g >> 2, ks = g & 3;
      int n = gc * 16 + lr;
      int kl = ks * 32 + lg * 8 + i;
      int ok = (kl & ~31) + ((kl & 31) >> 1) + ((kl & 1) << 4);
      v = Wt2[ok * 64 + n];
    }
    res[e2] = bf16r(v);
  }
  *(uint32_t*)(fb + (size_t)f * 512 + t * 2) = (uint32_t)res[0] | ((uint32_t)res[1] << 16);
}

// ---------------- user vector ----------------
__global__ void k_user(const int* __restrict__ hist, const int* __restrict__ wish,
                       const float* __restrict__ Eh, const float* __restrict__ Ew,
                       float* __restrict__ uv) {
  int t = threadIdx.x;
  int d = t & 31;
  int r = (blockIdx.x << 3) + (t >> 5);
  const int* hr = hist + r * LH;
  float s = 0.f;
  #pragma unroll 8
  for (int j = 0; j < LH; ++j) s += Eh[ntli(hr + j) * 32 + d];
  float su = s * (1.0f / LH);
  const int* wr = wish + r * LW;
  s = 0.f;
  #pragma unroll 5
  for (int j = 0; j < LW; ++j) s += Ew[ntli(wr + j) * 32 + d];
  uv[r * 32 + d] = su + s * (1.0f / LW);
}

// gather 2 dims (2*lr, 2*lr+1): compile-time bf16/f32 path
template<int BF>
__device__ __forceinline__ void g2t(const uint16_t* B, const float* F, int idx, int lr,
                                    float& a0, float& a1) {
  if constexpr (BF) {
    uint32_t g = *(const uint32_t*)((const char*)B + ((size_t)idx << 6) + (lr << 2));
    a0 = flo(g); a1 = fhi(g);
  } else {
    v2f e = *(const v2f*)(F + idx * 32 + 2 * lr);
    a0 = e[0]; a1 = e[1];
  }
}

// ---------------- fused item pipeline (5 barriers/tile) ----------------
#define SM_CONST 0       // 672 f32 = 2688 B
#define SM_X     2688    // [64][128B] = 8192
#define SM_H     10880   // [64][64B]  = 4096
#define SM_ACT1  14976   // [64][512B] = 32768 ; ACT2 aliases first 16384
#define SM_ACT2  14976   // [64][256B]
#define SM_IDX   47744   // 64 x 8 idx = 2048
#define SM_BYTES 49792
// cf: 0 bb1[32] | 32 bt0[256] | 288 bt1[128] | 416 bt2[64] | 480 bb0[32] | 512 Wb0[96] | 608 Wt3[64]

template<int TET, int TEC, int TEA, int TEL>
__global__ __launch_bounds__(256, 3)
void k_fused(const int* __restrict__ cand, const int* __restrict__ auth,
             const int* __restrict__ lang, const int* __restrict__ tags,
             const float* __restrict__ dense,
             const float* __restrict__ Ec, const float* __restrict__ Ea,
             const float* __restrict__ El, const float* __restrict__ Et,
             const uint16_t* __restrict__ EcB, const uint16_t* __restrict__ EaB,
             const uint16_t* __restrict__ ElB, const uint16_t* __restrict__ EtB,
             const float* __restrict__ Wb0, const float* __restrict__ bb0,
             const float* __restrict__ bb1, const float* __restrict__ bt0,
             const float* __restrict__ bt1, const float* __restrict__ bt2,
             const float* __restrict__ Wt3, const float* __restrict__ bt3,
             const float* __restrict__ uvec, const uint16_t* __restrict__ fw,
             float* __restrict__ out) {
  extern __shared__ char sm[];
  const char* fwp = (const char*)fw;
  float* cf = (float*)(sm + SM_CONST);
  const int t = threadIdx.x;
  const int l = t & 63, wv = t >> 6;
  const int lr = l & 15, lg = l >> 4;
  const int q = t & 3, rowl = t >> 2;

  // ---- stage constants (LDS) ----
  cf[32 + t] = bt0[t];
  if (t < 128) cf[288 + t] = bt1[t];
  if (t < 32)  { cf[t] = bb1[t]; cf[480 + t] = bb0[t]; }
  if (t < 96)  cf[512 + t] = Wb0[t];
  const float bt3v = bt3[0];

  // ---- loop-invariant registers (loaded from GLOBAL, no barrier needed) ----
  v8s wbl = *(const v8s*)(fwp + (size_t)(FRAG_B1 + 0) * 1024 + l * 16);
  v8s wbh = *(const v8s*)(fwp + (size_t)(FRAG_B1 + 1) * 1024 + l * 16);
  const float bb1r0 = bb1[2 * lr], bb1r1 = bb1[2 * lr + 1];
  const float wt3r0 = Wt3[lr],      wt3r1 = Wt3[16 + lr];
  const float wt3r2 = Wt3[32 + lr], wt3r3 = Wt3[48 + lr];
  const float bt2r0 = bt2[lr],      bt2r1 = bt2[16 + lr];
  const float bt2r2 = bt2[32 + lr], bt2r3 = bt2[48 + lr];

  // ---- stream prefetch state (one tile lookahead) ----
  float4 uf0, uf1;
  float d3x, d3y, d3z;
  int i2a, i2b;
  auto ld_tile = [&](int tl) {
    int rr0 = (tl << 6) + rowl;
    int b = rr0 / 100;
    uf0 = *(const float4*)(uvec + b * 32 + q * 8);
    uf1 = *(const float4*)(uvec + b * 32 + q * 8 + 4);
    d3x = ntlf(dense + rr0 * 3 + 0);
    d3y = ntlf(dense + rr0 * 3 + 1);
    d3z = ntlf(dense + rr0 * 3 + 2);
    int s0 = q * 2;
    i2a = (s0 == 0) ? ntli(cand + rr0) : (s0 == 2) ? ntli(lang + rr0)
        : (s0 == 4) ? ntli(tags + rr0 * 5 + 1) : ntli(tags + rr0 * 5 + 3);
    i2b = (s0 == 0) ? ntli(auth + rr0) : (s0 == 2) ? ntli(tags + rr0 * 5 + 0)
        : (s0 == 4) ? ntli(tags + rr0 * 5 + 2) : ntli(tags + rr0 * 5 + 4);
  };
  ld_tile(blockIdx.x);

  barx();   // constants staged

  for (int tile = blockIdx.x; tile < NTILES; tile += GRID_F) {
    const int r0 = tile << 6;

    // ---- P0: X u-part + idx->LDS + bottom-MLP layer0 (h) ----
    {
      int xrb = SM_X + rowl * 128;
      int sw  = (rowl & 7) << 4;
      float uu[8] = {uf0.x, uf0.y, uf0.z, uf0.w, uf1.x, uf1.y, uf1.z, uf1.w};
      #pragma unroll
      for (int k2 = 0; k2 < 4; ++k2)
        *(uint32_t*)(sm + xrb + ((q * 16 + k2 * 4) ^ sw)) = pkbf(uu[2*k2], uu[2*k2+1]);
      *(int*)(sm + SM_IDX + rowl * 32 + q * 8)     = i2a;
      *(int*)(sm + SM_IDX + rowl * 32 + q * 8 + 4) = i2b;
      const float* bb0l = cf + 480;
      const float* w0a = cf + 512, *w0b = cf + 544, *w0c = cf + 576;
      int hrb = SM_H + rowl * 64;
      int sw3 = (rowl & 3) << 4;
      #pragma unroll
      for (int u2 = 0; u2 < 4; ++u2) {
        int e0 = q * 8 + u2 * 2, e1 = e0 + 1;
        float h0 = fmaxf(bb0l[e0] + d3x * w0a[e0] + d3y * w0b[e0] + d3z * w0c[e0], 0.f);
        float h1 = fmaxf(bb0l[e1] + d3x * w0a[e1] + d3y * w0b[e1] + d3z * w0c[e1], 0.f);
        *(uint32_t*)(sm + hrb + ((q * 16 + u2 * 4) ^ sw3)) = pkbf(h0, h1);
      }
    }
    barx();

    // streams for t+1: in flight across barriers
    if (tile + GRID_F < NTILES) ld_tile(tile + GRID_F);

    // t0 frag prefetch: issued here, consumed after next barrier
    v8s fr0[8];
    #pragma unroll
    for (int i = 0; i < 8; ++i)
      fr0[i] = *(const v8s*)(fwp + (size_t)(FRAG_T0 + wv * 8 + i) * 1024 + l * 16);

    // ---- P1: b1 MFMA (d_vec) + gathers -> X i-part ----
    {
      int hrow = 16 * wv + lr;
      v8s ah = *(const v8s*)(sm + SM_H + hrow * 64 + ((lg * 16) ^ ((hrow & 3) << 4)));
      v4f dv0 = {bb1r0, bb1r0, bb1r0, bb1r0};
      v4f dv1 = {bb1r1, bb1r1, bb1r1, bb1r1};
      dv0 = mfma16(ah, wbl, dv0);   // i dims 2*lr
      dv1 = mfma16(ah, wbh, dv1);   // i dims 2*lr+1
      #pragma unroll
      for (int j = 0; j < 4; ++j) {
        int mrow = 16 * wv + lg * 4 + j;
        const int* ip = (const int*)(sm + SM_IDX + mrow * 32);
        int ic = ip[0], ia = ip[1], il = ip[2];
        int t0i = ip[3], t1i = ip[4], t2i = ip[5], t3i = ip[6], t4i = ip[7];
        float c0, c1, a0, a1, l0, l1, p0, p1, p2, p3, p4, p5, p6, p7, p8, p9;
        g2t<TEC>(EcB, Ec, ic,  lr, c0, c1);
        g2t<TEA>(EaB, Ea, ia,  lr, a0, a1);
        g2t<TEL>(ElB, El, il,  lr, l0, l1);
        g2t<TET>(EtB, Et, t0i, lr, p0, p1);
        g2t<TET>(EtB, Et, t1i, lr, p2, p3);
        g2t<TET>(EtB, Et, t2i, lr, p4, p5);
        g2t<TET>(EtB, Et, t3i, lr, p6, p7);
        g2t<TET>(EtB, Et, t4i, lr, p8, p9);
        float s0 = c0 + a0 + l0 + (p0 + p2 + p4 + p6 + p8) * 0.2f + dv0[j];
        float s1 = c1 + a1 + l1 + (p1 + p3 + p5 + p7 + p9) * 0.2f + dv1[j];
        *(uint32_t*)(sm + SM_X + mrow * 128 + ((64 + 4 * lr) ^ ((mrow & 7) << 4))) = pkbf(s0, s1);
      }
    }
    barx();

    // ---- t0 (64->256): both 128-col chunks, one barrier ----
    #pragma unroll
    for (int ch = 0; ch < 2; ++ch) {
      v4f a1[2][4];
      #pragma unroll
      for (int p = 0; p < 2; ++p) {
        float bv = cf[32 + ch * 128 + wv * 32 + p * 16 + lr];
        #pragma unroll
        for (int m = 0; m < 4; ++m) a1[p][m] = (v4f){bv, bv, bv, bv};
      }
      #pragma unroll
      for (int ks = 0; ks < 2; ++ks) {
        v8s xa[4];
        #pragma unroll
        for (int m = 0; m < 4; ++m)
          xa[m] = *(const v8s*)(sm + SM_X + (m * 16 + lr) * 128 + ((ks * 64 + lg * 16) ^ ((lr & 7) << 4)));
        #pragma unroll
        for (int p = 0; p < 2; ++p) {
          #pragma unroll
          for (int m = 0; m < 4; ++m) a1[p][m] = mfma16(xa[m], fr0[ch * 4 + ks * 2 + p], a1[p][m]);
        }
      }
      #pragma unroll
      for (int m = 0; m < 4; ++m) {
        #pragma unroll
        for (int j = 0; j < 4; ++j) {
          int row = m * 16 + lg * 4 + j;
          *(uint32_t*)(sm + SM_ACT1 + row * 512 + ((ch * 256 + wv * 64 + 4 * lr) ^ ((row & 7) << 4)))
            = pkbf(fmaxf(a1[0][m][j], 0.f), fmaxf(a1[1][m][j], 0.f));
        }
      }
    }
    // t1 frag prefetch across the barrier
    v8s fr1[16];
    #pragma unroll
    for (int i = 0; i < 16; ++i)
      fr1[i] = *(const v8s*)(fwp + (size_t)(FRAG_T1 + wv * 16 + i) * 1024 + l * 16);
    barx();

    // ---- t1 (256->128): acc in regs ----
    v4f acc2[2][4];
    #pragma unroll
    for (int p = 0; p < 2; ++p) {
      float bv = cf[288 + wv * 32 + p * 16 + lr];
      #pragma unroll
      for (int m = 0; m < 4; ++m) acc2[p][m] = (v4f){bv, bv, bv, bv};
    }
    #pragma unroll
    for (int ch = 0; ch < 2; ++ch) {
      #pragma unroll
      for (int ks = 0; ks < 4; ++ks) {
        v8s aa[4];
        #pragma unroll
        for (int m = 0; m < 4; ++m)
          aa[m] = *(const v8s*)(sm + SM_ACT1 + (m * 16 + lr) * 512 + ((ch * 256 + ks * 64 + lg * 16) ^ ((lr & 7) << 4)));
        #pragma unroll
        for (int p = 0; p < 2; ++p) {
          #pragma unroll
          for (int m = 0; m < 4; ++m) acc2[p][m] = mfma16(aa[m], fr1[ch * 8 + ks * 2 + p], acc2[p][m]);
        }
      }
    }
    barx();   // ACT1 dead

    // ---- act2 write (relu, paired) + t2 frag prefetch ----
    #pragma unroll
    for (int m = 0; m < 4; ++m) {
      #pragma unroll
      for (int j = 0; j < 4; ++j) {
        int row = m * 16 + lg * 4 + j;
        *(uint32_t*)(sm + SM_ACT2 + row * 256 + ((wv * 64 + 4 * lr) ^ ((row & 7) << 4)))
          = pkbf(fmaxf(acc2[0][m][j], 0.f), fmaxf(acc2[1][m][j], 0.f));
      }
    }
    v8s fr2[16];
    #pragma unroll
    for (int i = 0; i < 16; ++i)
      fr2[i] = *(const v8s*)(fwp + (size_t)(FRAG_T2 + i) * 1024 + l * 16);
    barx();

    // ---- t2+t3 fused: wave owns rows 16wv..16wv+15, all 64 cols; dot in regs ----
    {
      int arow = 16 * wv + lr;
      v4f a3[4] = {{bt2r0, bt2r0, bt2r0, bt2r0}, {bt2r1, bt2r1, bt2r1, bt2r1},
                   {bt2r2, bt2r2, bt2r2, bt2r2}, {bt2r3, bt2r3, bt2r3, bt2r3}};
      #pragma unroll
      for (int ks = 0; ks < 4; ++ks) {
        v8s aa = *(const v8s*)(sm + SM_ACT2 + arow * 256 + ((ks * 64 + lg * 16) ^ ((arow & 7) << 4)));
        #pragma unroll
        for (int g = 0; g < 4; ++g) a3[g] = mfma16(aa, fr2[g * 4 + ks], a3[g]);
      }
      float o[4];
      #pragma unroll
      for (int j = 0; j < 4; ++j) {
        o[j] = fmaxf(a3[0][j], 0.f) * wt3r0 + fmaxf(a3[1][j], 0.f) * wt3r1
             + fmaxf(a3[2][j], 0.f) * wt3r2 + fmaxf(a3[3][j], 0.f) * wt3r3;
        o[j] += __shfl_xor(o[j], 1);
        o[j] += __shfl_xor(o[j], 2);
        o[j] += __shfl_xor(o[j], 4);
        o[j] += __shfl_xor(o[j], 8);
      }
      if (lr == 0) {
        float4 ov = {o[0] + bt3v, o[1] + bt3v, o[2] + bt3v, o[3] + bt3v};
        *(float4*)(out + r0 + wv * 16 + lg * 4) = ov;
      }
    }
    // no barrier: next P0 writes X/H/IDX (disjoint from ACT2); P0-bar orders everything
  }
}

extern "C" void kernel_launch(void* const* d_in, const int* in_sizes, int n_in,
                              void* d_out, int out_size, void* d_ws, size_t ws_size,
                              hipStream_t stream) {
  const int*   hist  = (const int*)d_in[0];
  const int*   wish  = (const int*)d_in[1];
  const int*   cand  = (const int*)d_in[2];
  const int*   auth  = (const int*)d_in[3];
  const int*   lang  = (const int*)d_in[4];
  const int*   tags  = (const int*)d_in[5];
  const float* dense = (const float*)d_in[6];
  const float* Eh    = (const float*)d_in[7];
  const float* Ew    = (const float*)d_in[8];
  const float* Ec    = (const float*)d_in[9];
  const float* Ea    = (const float*)d_in[10];
  const float* El    = (const float*)d_in[11];
  const float* Et    = (const float*)d_in[12];
  const float* Wb0   = (const float*)d_in[13];
  const float* bb0   = (const float*)d_in[14];
  const float* Wb1   = (const float*)d_in[15];
  const float* bb1   = (const float*)d_in[16];
  const float* Wt0   = (const float*)d_in[17];
  const float* bt0   = (const float*)d_in[18];
  const float* Wt1   = (const float*)d_in[19];
  const float* bt1   = (const float*)d_in[20];
  const float* Wt2   = (const float*)d_in[21];
  const float* bt2   = (const float*)d_in[22];
  const float* Wt3   = (const float*)d_in[23];
  const float* bt3   = (const float*)d_in[24];
  char* wsb = (char*)d_ws;
  float* out = (float*)d_out;

  float*    uv = (float*)(wsb + OFF_UV);
  uint16_t* fw = (uint16_t*)(wsb + OFF_FW);

  k_prep<<<NFRAGS, 256, 0, stream>>>(Wb1, Wt0, Wt1, Wt2, fw);
  k_user<<<NB / 8, 256, 0, stream>>>(hist, wish, Eh, Ew, uv);

  size_t off = OFF_TB;
  uint16_t *EtB = nullptr, *EcB = nullptr, *EaB = nullptr, *ElB = nullptr;
  if (ws_size >= (size_t)WS_ALL4) {
    EtB = (uint16_t*)(wsb + off); off += ET_BYTES;
    EcB = (uint16_t*)(wsb + off); off += EC_BYTES;
    EaB = (uint16_t*)(wsb + off); off += EA_BYTES;
    ElB = (uint16_t*)(wsb + off);
    k_cvt1<<<(34253*4 + 255)/256, 256, 0, stream>>>(Et, (uint32_t*)EtB, 34253*4);
    k_cvt1<<<(10001*4 + 255)/256, 256, 0, stream>>>(Ec, (uint32_t*)EcB, 10001*4);
    k_cvt1<<<(5001*4 + 255)/256, 256, 0, stream>>>(Ea, (uint32_t*)EaB, 5001*4);
    k_cvt1<<<1, 256, 0, stream>>>(El, (uint32_t*)ElB, 28*4);
    auto kf = k_fused<1,1,1,1>;
    (void)hipFuncSetAttribute((const void*)kf, hipFuncAttributeMaxDynamicSharedMemorySize, SM_BYTES);
    kf<<<GRID_F, 256, SM_BYTES, stream>>>(cand, auth, lang, tags, dense,
        Ec, Ea, El, Et, EcB, EaB, ElB, EtB, Wb0, bb0, bb1, bt0, bt1, bt2, Wt3, bt3, uv, fw, out);
  } else if (ws_size >= (size_t)WS_CAL) {
    EcB = (uint16_t*)(wsb + off); off += EC_BYTES;
    EaB = (uint16_t*)(wsb + off); off += EA_BYTES;
    ElB = (uint16_t*)(wsb + off);
    k_cvt1<<<(10001*4 + 255)/256, 256, 0, stream>>>(Ec, (uint32_t*)EcB, 10001*4);
    k_cvt1<<<(5001*4 + 255)/256, 256, 0, stream>>>(Ea, (uint32_t*)EaB, 5001*4);
    k_cvt1<<<1, 256, 0, stream>>>(El, (uint32_t*)ElB, 28*4);
    auto kf = k_fused<0,1,1,1>;
    (void)hipFuncSetAttribute((const void*)kf, hipFuncAttributeMaxDynamicSharedMemorySize, SM_BYTES);
    kf<<<GRID_F, 256, SM_BYTES, stream>>>(cand, auth, lang, tags, dense,
        Ec, Ea, El, Et, EcB, EaB, ElB, EtB, Wb0, bb0, bb1, bt0, bt1, bt2, Wt3, bt3, uv, fw, out);
  } else if (ws_size >= (size_t)WS_AL) {
    EaB = (uint16_t*)(wsb + off); off += EA_BYTES;
    ElB = (uint16_t*)(wsb + off);
    k_cvt1<<<(5001*4 + 255)/256, 256, 0, stream>>>(Ea, (uint32_t*)EaB, 5001*4);
    k_cvt1<<<1, 256, 0, stream>>>(El, (uint32_t*)ElB, 28*4);
    auto kf = k_fused<0,0,1,1>;
    (void)hipFuncSetAttribute((const void*)kf, hipFuncAttributeMaxDynamicSharedMemorySize, SM_BYTES);
    kf<<<GRID_F, 256, SM_BYTES, stream>>>(cand, auth, lang, tags, dense,
        Ec, Ea, El, Et, EcB, EaB, ElB, EtB, Wb0, bb0, bb1, bt0, bt1, bt2, Wt3, bt3, uv, fw, out);
  } else {
    auto kf = k_fused<0,0,0,0>;
    (void)hipFuncSetAttribute((const void*)kf, hipFuncAttributeMaxDynamicSharedMemorySize, SM_BYTES);
    kf<<<GRID_F, 256, SM_BYTES, stream>>>(cand, auth, lang, tags, dense,
        Ec, Ea, El, Et, EcB, EaB, ElB, EtB, Wb0, bb0, bb1, bt0, bt1, bt2, Wt3, bt3, uv, fw, out);
  }
}

// Round 7
// 325.435 us; speedup vs baseline: 1.4303x; 1.4303x over previous
//
#include <hip/hip_runtime.h>
#include <hip/hip_bf16.h>
#include <stdint.h>

#define NB 4096
#define NC 100
#define NROWS (NB*NC)        // 409600
#define NTILES (NROWS/64)    // 6400
#define GRID_F 768
#define LH 200
#define LW 50

typedef short v8s __attribute__((ext_vector_type(8)));
typedef float v4f __attribute__((ext_vector_type(4)));
typedef float v2f __attribute__((ext_vector_type(2)));
typedef uint32_t v4u __attribute__((ext_vector_type(4)));

__device__ __forceinline__ v4f mfma16(v8s a, v8s b, v4f c) {
  return __builtin_amdgcn_mfma_f32_16x16x32_bf16(a, b, c, 0, 0, 0);
}

// packed f32x2 -> bf16x2 (lo = first arg), RNE
__device__ __forceinline__ uint32_t pkbf(float lo, float hi) {
  uint32_t r;
  asm("v_cvt_pk_bf16_f32 %0, %1, %2" : "=v"(r) : "v"(lo), "v"(hi));
  return r;
}

__device__ __forceinline__ uint16_t bf16r(float f) {
  uint32_t u = __builtin_bit_cast(uint32_t, f);
  u = (u + 0x7fffu + ((u >> 16) & 1u)) >> 16;
  return (uint16_t)u;
}

__device__ __forceinline__ int ntli(const int* p) { return __builtin_nontemporal_load(p); }
__device__ __forceinline__ float ntlf(const float* p) { return __builtin_nontemporal_load(p); }

// barrier that does NOT drain vmcnt: LDS-safe (lgkmcnt), global loads stay in flight
__device__ __forceinline__ void barx() {
  asm volatile("s_waitcnt lgkmcnt(0)" ::: "memory");
  __builtin_amdgcn_s_barrier();
  asm volatile("" ::: "memory");
}

// ---------------- workspace layout ----------------
// [0,256K) uvb bf16-paired | [256K, 383K) weight frags
#define OFF_UVB 0
#define OFF_FW  262144

#define FRAG_B1 0     // 2 frags (even/odd output cols)
#define FRAG_T0 2     // 32 frags: g = wv*8 + ch*4 + ks*2 + p   (k identity)
#define FRAG_T1 34    // 64 frags: g = wv*16 + ch*8 + ks*2 + p  (k PERM32-paired)
#define FRAG_T2 98    // 16 frags: g = gcol*4 + ks              (k PERM32-paired, n=gcol*16+lr)
#define NFRAGS 114

// ---------------- build weight B-fragments ----------------
__global__ void k_prep(const float* __restrict__ Wb1, const float* __restrict__ Wt0,
                       const float* __restrict__ Wt1, const float* __restrict__ Wt2,
                       uint16_t* __restrict__ fb) {
  int f = blockIdx.x;
  int t = threadIdx.x;
  uint16_t res[2];
  #pragma unroll
  for (int e2 = 0; e2 < 2; ++e2) {
    int e = t * 2 + e2;        // 0..511
    int l = e >> 3, i = e & 7;
    int lr = l & 15, lg = l >> 4;
    float v;
    if (f < FRAG_T0) {                       // Wb1: frag f holds output cols 2*lr+f
      v = Wb1[(lg * 8 + i) * 32 + 2 * lr + f];
    } else if (f < FRAG_T1) {                // Wt0 (k identity)
      int g = f - FRAG_T0;
      int wv = g >> 3, ch = (g >> 2) & 1, ks = (g >> 1) & 1, p = g & 1;
      int n = ch * 128 + wv * 32 + p * 16 + lr;
      int kl = ks * 32 + lg * 8 + i;
      v = Wt0[kl * 256 + n];
    } else if (f < FRAG_T2) {                // Wt1 (act1 pkbf-paired)
      int g = f - FRAG_T1;
      int wv = g >> 4, ch = (g >> 3) & 1, ks = (g >> 1) & 3, p = g & 1;
      int n = wv * 32 + p * 16 + lr;
      int kl = ks * 32 + lg * 8 + i;
      int ok = ch * 128 + (kl & ~31) + ((kl & 31) >> 1) + ((kl & 1) << 4);
      v = Wt1[ok * 128 + n];
    } else {                                 // Wt2 (act2 pkbf-paired)
      int g = f - FRAG_T2;
      int gc = g >> 2, ks = g & 3;
      int n = gc * 16 + lr;
      int kl = ks * 32 + lg * 8 + i;
      int ok = (kl & ~31) + ((kl & 31) >> 1) + ((kl & 1) << 4);
      v = Wt2[ok * 64 + n];
    }
    res[e2] = bf16r(v);
  }
  *(uint32_t*)(fb + (size_t)f * 512 + t * 2) = (uint32_t)res[0] | ((uint32_t)res[1] << 16);
}

// ---------------- user vector -> bf16-paired uvb ----------------
__global__ void k_user_bf(const int* __restrict__ hist, const int* __restrict__ wish,
                          const float* __restrict__ Eh, const float* __restrict__ Ew,
                          uint32_t* __restrict__ uvb) {
  int t = threadIdx.x;
  int d2 = t & 15;                    // dim pair (2*d2, 2*d2+1)
  int r = blockIdx.x * 16 + (t >> 4);
  const int* hr = hist + r * LH;
  float sl = 0.f, sh = 0.f;
  #pragma unroll 8
  for (int j = 0; j < LH; ++j) {
    v2f e = *(const v2f*)(Eh + ntli(hr + j) * 32 + 2 * d2);
    sl += e[0]; sh += e[1];
  }
  const int* wr = wish + r * LW;
  float wl = 0.f, wh = 0.f;
  #pragma unroll 5
  for (int j = 0; j < LW; ++j) {
    v2f e = *(const v2f*)(Ew + ntli(wr + j) * 32 + 2 * d2);
    wl += e[0]; wh += e[1];
  }
  uvb[r * 16 + d2] = pkbf(sl * (1.0f/LH) + wl * (1.0f/LW), sh * (1.0f/LH) + wh * (1.0f/LW));
}

// ---------------- fused item pipeline (6 barriers/tile, depth-2 gather pipeline) ----------------
#define SM_CONST 0       // 672 f32 = 2688 B
#define SM_X     2688    // [64][128B] = 8192
#define SM_H     10880   // [64][64B]  = 4096
#define SM_ACT1  14976   // [64][512B] = 32768 ; ACT2 aliases first 16384
#define SM_ACT2  14976   // [64][256B]
#define SM_IDX   47744   // 64 x 8 idx x 4B = 2048
#define SM_BYTES 49792
// cf: 0 bb1[32] | 32 bt0[256] | 288 bt1[128] | 416 bt2[64] | 480 bb0[32] | 512 Wb0[96] | 608 Wt3[64]

__global__ __launch_bounds__(256, 3)
void k_fused(const int* __restrict__ cand, const int* __restrict__ auth,
             const int* __restrict__ lang, const int* __restrict__ tags,
             const float* __restrict__ dense,
             const float* __restrict__ Ec, const float* __restrict__ Ea,
             const float* __restrict__ El, const float* __restrict__ Et,
             const float* __restrict__ Wb0, const float* __restrict__ bb0,
             const float* __restrict__ bb1, const float* __restrict__ bt0,
             const float* __restrict__ bt1, const float* __restrict__ bt2,
             const float* __restrict__ Wt3, const float* __restrict__ bt3,
             const uint32_t* __restrict__ uvb, const uint16_t* __restrict__ fw,
             float* __restrict__ out) {
  extern __shared__ char sm[];
  const char* fwp = (const char*)fw;
  float* cf = (float*)(sm + SM_CONST);
  const int t = threadIdx.x;
  const int l = t & 63, wv = t >> 6;
  const int lr = l & 15, lg = l >> 4;
  const int q = t & 3, rowl = t >> 2;

  // ---- stage constants (LDS) ----
  cf[32 + t] = bt0[t];
  if (t < 128) cf[288 + t] = bt1[t];
  if (t < 64)  { cf[416 + t] = bt2[t]; cf[608 + t] = Wt3[t]; }
  if (t < 32)  { cf[t] = bb1[t]; cf[480 + t] = bb0[t]; }
  if (t < 96)  cf[512 + t] = Wb0[t];
  const float bt3v = bt3[0];

  // loop-invariant b1 weight fragments (global, L2-hot)
  v8s wbl = *(const v8s*)(fwp + (size_t)(FRAG_B1 + 0) * 1024 + l * 16);
  v8s wbh = *(const v8s*)(fwp + (size_t)(FRAG_B1 + 1) * 1024 + l * 16);

  // ---- pipelined stream + gather state ----
  v4u u4;                 // uv pairs, tile t (consumed P0)
  float d3x, d3y, d3z;    // dense, tile t (consumed P0)
  int i2a, i2b;           // idx for tile t+G (written to IDX at P0)
  v2f gc[4], ga[4], gl[4], gt0[4], gt1[4], gt2[4], gt3[4], gt4[4];  // gathers, tile t

  auto ld_uv = [&](int tl) {
    int rr0 = (tl << 6) + rowl;
    int b = rr0 / 100;
    u4 = *(const v4u*)(uvb + b * 16 + q * 4);
    d3x = ntlf(dense + rr0 * 3 + 0);
    d3y = ntlf(dense + rr0 * 3 + 1);
    d3z = ntlf(dense + rr0 * 3 + 2);
  };
  auto ld_idx = [&](int tl) {
    int rr0 = (tl << 6) + rowl;
    int s0 = q * 2;
    i2a = (s0 == 0) ? ntli(cand + rr0) : (s0 == 2) ? ntli(lang + rr0)
        : (s0 == 4) ? ntli(tags + rr0 * 5 + 1) : ntli(tags + rr0 * 5 + 3);
    i2b = (s0 == 0) ? ntli(auth + rr0) : (s0 == 2) ? ntli(tags + rr0 * 5 + 0)
        : (s0 == 4) ? ntli(tags + rr0 * 5 + 2) : ntli(tags + rr0 * 5 + 4);
  };
  auto issue_gathers = [&]() {   // reads IDX (indices of the NEXT tile), issues 32 loads
    #pragma unroll
    for (int j = 0; j < 4; ++j) {
      int mrow = 16 * wv + lg * 4 + j;
      const int* ip = (const int*)(sm + SM_IDX + mrow * 32);
      int ic = ip[0], ia = ip[1], il = ip[2];
      int x0 = ip[3], x1 = ip[4], x2 = ip[5], x3 = ip[6], x4 = ip[7];
      gc[j]  = *(const v2f*)(Ec + ic * 32 + 2 * lr);
      ga[j]  = *(const v2f*)(Ea + ia * 32 + 2 * lr);
      gl[j]  = *(const v2f*)(El + il * 32 + 2 * lr);
      gt0[j] = *(const v2f*)(Et + x0 * 32 + 2 * lr);
      gt1[j] = *(const v2f*)(Et + x1 * 32 + 2 * lr);
      gt2[j] = *(const v2f*)(Et + x2 * 32 + 2 * lr);
      gt3[j] = *(const v2f*)(Et + x3 * 32 + 2 * lr);
      gt4[j] = *(const v2f*)(Et + x4 * 32 + 2 * lr);
    }
  };

  // ---- prologue: prime the pipeline for tile0 ----
  const int tile0 = blockIdx.x;
  ld_idx(tile0);
  *(int*)(sm + SM_IDX + rowl * 32 + q * 8)     = i2a;
  *(int*)(sm + SM_IDX + rowl * 32 + q * 8 + 4) = i2b;
  barx();                 // covers cf staging + IDX
  issue_gathers();        // gathers for tile0 (one-time exposed latency)
  ld_uv(tile0);
  { int n1 = tile0 + GRID_F; if (n1 > NTILES - 1) n1 = NTILES - 1; ld_idx(n1); }

  for (int tile = tile0; tile < NTILES; tile += GRID_F) {
    const int r0 = tile << 6;

    // ---- P0: X u-part + IDX(t+G) + bottom-MLP layer0 (h) ----
    {
      int xrb = SM_X + rowl * 128;
      int sw  = (rowl & 7) << 4;
      #pragma unroll
      for (int k2 = 0; k2 < 4; ++k2)
        *(uint32_t*)(sm + xrb + ((q * 16 + k2 * 4) ^ sw)) = u4[k2];
      *(int*)(sm + SM_IDX + rowl * 32 + q * 8)     = i2a;
      *(int*)(sm + SM_IDX + rowl * 32 + q * 8 + 4) = i2b;
      const float* bb0l = cf + 480;
      const float* w0a = cf + 512, *w0b = cf + 544, *w0c = cf + 576;
      int hrb = SM_H + rowl * 64;
      int sw3 = (rowl & 3) << 4;
      #pragma unroll
      for (int u2 = 0; u2 < 4; ++u2) {
        int e0 = q * 8 + u2 * 2, e1 = e0 + 1;
        float h0 = fmaxf(bb0l[e0] + d3x * w0a[e0] + d3y * w0b[e0] + d3z * w0c[e0], 0.f);
        float h1 = fmaxf(bb0l[e1] + d3x * w0a[e1] + d3y * w0b[e1] + d3z * w0c[e1], 0.f);
        *(uint32_t*)(sm + hrb + ((q * 16 + u2 * 4) ^ sw3)) = pkbf(h0, h1);
      }
    }
    barx();

    // ---- P1: b1 MFMA (d_vec) + consume pipelined gathers -> X i-part ----
    {
      int hrow = 16 * wv + lr;
      v8s ah = *(const v8s*)(sm + SM_H + hrow * 64 + ((lg * 16) ^ ((hrow & 3) << 4)));
      float b0v = cf[2 * lr], b1v = cf[2 * lr + 1];
      v4f dv0 = {b0v, b0v, b0v, b0v};
      v4f dv1 = {b1v, b1v, b1v, b1v};
      dv0 = mfma16(ah, wbl, dv0);   // i dims 2*lr
      dv1 = mfma16(ah, wbh, dv1);   // i dims 2*lr+1
      #pragma unroll
      for (int j = 0; j < 4; ++j) {
        int mrow = 16 * wv + lg * 4 + j;
        float s0 = gc[j][0] + ga[j][0] + gl[j][0]
                 + (gt0[j][0] + gt1[j][0] + gt2[j][0] + gt3[j][0] + gt4[j][0]) * 0.2f + dv0[j];
        float s1 = gc[j][1] + ga[j][1] + gl[j][1]
                 + (gt0[j][1] + gt1[j][1] + gt2[j][1] + gt3[j][1] + gt4[j][1]) * 0.2f + dv1[j];
        *(uint32_t*)(sm + SM_X + mrow * 128 + ((64 + 4 * lr) ^ ((mrow & 7) << 4))) = pkbf(s0, s1);
      }
    }
    barx();

    // ---- t0 (64->256): inline frags, both chunks, one barrier ----
    #pragma unroll
    for (int ch = 0; ch < 2; ++ch) {
      v4f a1[2][4];
      #pragma unroll
      for (int p = 0; p < 2; ++p) {
        float bv = cf[32 + ch * 128 + wv * 32 + p * 16 + lr];
        #pragma unroll
        for (int m = 0; m < 4; ++m) a1[p][m] = (v4f){bv, bv, bv, bv};
      }
      #pragma unroll
      for (int ks = 0; ks < 2; ++ks) {
        v8s f0 = *(const v8s*)(fwp + (size_t)(FRAG_T0 + wv * 8 + ch * 4 + ks * 2 + 0) * 1024 + l * 16);
        v8s f1 = *(const v8s*)(fwp + (size_t)(FRAG_T0 + wv * 8 + ch * 4 + ks * 2 + 1) * 1024 + l * 16);
        #pragma unroll
        for (int m = 0; m < 4; ++m) {
          v8s xa = *(const v8s*)(sm + SM_X + (m * 16 + lr) * 128 + ((ks * 64 + lg * 16) ^ ((lr & 7) << 4)));
          a1[0][m] = mfma16(xa, f0, a1[0][m]);
          a1[1][m] = mfma16(xa, f1, a1[1][m]);
        }
      }
      #pragma unroll
      for (int m = 0; m < 4; ++m) {
        #pragma unroll
        for (int j = 0; j < 4; ++j) {
          int row = m * 16 + lg * 4 + j;
          *(uint32_t*)(sm + SM_ACT1 + row * 512 + ((ch * 256 + wv * 64 + 4 * lr) ^ ((row & 7) << 4)))
            = pkbf(fmaxf(a1[0][m][j], 0.f), fmaxf(a1[1][m][j], 0.f));
        }
      }
    }
    barx();

    // ---- t1 (256->128): inline frags, per-m ds_reads ----
    v4f acc2[2][4];
    #pragma unroll
    for (int p = 0; p < 2; ++p) {
      float bv = cf[288 + wv * 32 + p * 16 + lr];
      #pragma unroll
      for (int m = 0; m < 4; ++m) acc2[p][m] = (v4f){bv, bv, bv, bv};
    }
    #pragma unroll
    for (int ch = 0; ch < 2; ++ch) {
      #pragma unroll
      for (int ks = 0; ks < 4; ++ks) {
        v8s f0 = *(const v8s*)(fwp + (size_t)(FRAG_T1 + wv * 16 + ch * 8 + ks * 2 + 0) * 1024 + l * 16);
        v8s f1 = *(const v8s*)(fwp + (size_t)(FRAG_T1 + wv * 16 + ch * 8 + ks * 2 + 1) * 1024 + l * 16);
        #pragma unroll
        for (int m = 0; m < 4; ++m) {
          v8s aa = *(const v8s*)(sm + SM_ACT1 + (m * 16 + lr) * 512 + ((ch * 256 + ks * 64 + lg * 16) ^ ((lr & 7) << 4)));
          acc2[0][m] = mfma16(aa, f0, acc2[0][m]);
          acc2[1][m] = mfma16(aa, f1, acc2[1][m]);
        }
      }
    }
    barx();   // ACT1 dead

    // ---- act2 write (relu, paired) ----
    #pragma unroll
    for (int m = 0; m < 4; ++m) {
      #pragma unroll
      for (int j = 0; j < 4; ++j) {
        int row = m * 16 + lg * 4 + j;
        *(uint32_t*)(sm + SM_ACT2 + row * 256 + ((wv * 64 + 4 * lr) ^ ((row & 7) << 4)))
          = pkbf(fmaxf(acc2[0][m][j], 0.f), fmaxf(acc2[1][m][j], 0.f));
      }
    }
    barx();

    // ---- t2 (inline frags) + prefetch issue + t3 ----
    {
      int arow = 16 * wv + lr;
      float bv0 = cf[416 + lr],      bv1 = cf[416 + 16 + lr];
      float bv2 = cf[416 + 32 + lr], bv3 = cf[416 + 48 + lr];
      v4f a3[4] = {{bv0, bv0, bv0, bv0}, {bv1, bv1, bv1, bv1},
                   {bv2, bv2, bv2, bv2}, {bv3, bv3, bv3, bv3}};
      #pragma unroll
      for (int ks = 0; ks < 4; ++ks) {
        v8s aa = *(const v8s*)(sm + SM_ACT2 + arow * 256 + ((ks * 64 + lg * 16) ^ ((arow & 7) << 4)));
        #pragma unroll
        for (int g = 0; g < 4; ++g) {
          v8s fg = *(const v8s*)(fwp + (size_t)(FRAG_T2 + g * 4 + ks) * 1024 + l * 16);
          a3[g] = mfma16(aa, fg, a3[g]);
        }
      }

      // issue next tile's streams + gathers (newest VMEM; in flight across end barrier)
      int n1 = tile + GRID_F;     if (n1 > NTILES - 1) n1 = NTILES - 1;
      int n2 = tile + 2 * GRID_F; if (n2 > NTILES - 1) n2 = NTILES - 1;
      ld_uv(n1);
      ld_idx(n2);
      issue_gathers();   // for tile n1 (reads IDX written at this tile's P0)

      // t3: in-register dot + 16-lane reduce, coalesced 64B store per wave
      float wr0 = cf[608 + lr],      wr1 = cf[608 + 16 + lr];
      float wr2 = cf[608 + 32 + lr], wr3 = cf[608 + 48 + lr];
      float o[4];
      #pragma unroll
      for (int j = 0; j < 4; ++j) {
        o[j] = fmaxf(a3[0][j], 0.f) * wr0 + fmaxf(a3[1][j], 0.f) * wr1
             + fmaxf(a3[2][j], 0.f) * wr2 + fmaxf(a3[3][j], 0.f) * wr3;
        o[j] += __shfl_xor(o[j], 1);
        o[j] += __shfl_xor(o[j], 2);
        o[j] += __shfl_xor(o[j], 4);
        o[j] += __shfl_xor(o[j], 8);
      }
      if (lr == 0) {
        float4 ov = {o[0] + bt3v, o[1] + bt3v, o[2] + bt3v, o[3] + bt3v};
        *(float4*)(out + r0 + wv * 16 + lg * 4) = ov;
      }
    }
    barx();   // protects IDX (read above) from next P0's overwrite
  }
}

extern "C" void kernel_launch(void* const* d_in, const int* in_sizes, int n_in,
                              void* d_out, int out_size, void* d_ws, size_t ws_size,
                              hipStream_t stream) {
  const int*   hist  = (const int*)d_in[0];
  const int*   wish  = (const int*)d_in[1];
  const int*   cand  = (const int*)d_in[2];
  const int*   auth  = (const int*)d_in[3];
  const int*   lang  = (const int*)d_in[4];
  const int*   tags  = (const int*)d_in[5];
  const float* dense = (const float*)d_in[6];
  const float* Eh    = (const float*)d_in[7];
  const float* Ew    = (const float*)d_in[8];
  const float* Ec    = (const float*)d_in[9];
  const float* Ea    = (const float*)d_in[10];
  const float* El    = (const float*)d_in[11];
  const float* Et    = (const float*)d_in[12];
  const float* Wb0   = (const float*)d_in[13];
  const float* bb0   = (const float*)d_in[14];
  const float* Wb1   = (const float*)d_in[15];
  const float* bb1   = (const float*)d_in[16];
  const float* Wt0   = (const float*)d_in[17];
  const float* bt0   = (const float*)d_in[18];
  const float* Wt1   = (const float*)d_in[19];
  const float* bt1   = (const float*)d_in[20];
  const float* Wt2   = (const float*)d_in[21];
  const float* bt2   = (const float*)d_in[22];
  const float* Wt3   = (const float*)d_in[23];
  const float* bt3   = (const float*)d_in[24];
  char* wsb = (char*)d_ws;
  float* out = (float*)d_out;

  uint32_t* uvb = (uint32_t*)(wsb + OFF_UVB);
  uint16_t* fw  = (uint16_t*)(wsb + OFF_FW);

  (void)hipFuncSetAttribute((const void*)k_fused,
                            hipFuncAttributeMaxDynamicSharedMemorySize, SM_BYTES);

  k_prep<<<NFRAGS, 256, 0, stream>>>(Wb1, Wt0, Wt1, Wt2, fw);
  k_user_bf<<<NB / 16, 256, 0, stream>>>(hist, wish, Eh, Ew, uvb);
  k_fused<<<GRID_F, 256, SM_BYTES, stream>>>(cand, auth, lang, tags, dense,
      Ec, Ea, El, Et, Wb0, bb0, bb1, bt0, bt1, bt2, Wt3, bt3, uvb, fw, out);
}

// Round 8
// 289.218 us; speedup vs baseline: 1.6094x; 1.1252x over previous
//
#include <hip/hip_runtime.h>
#include <hip/hip_bf16.h>
#include <stdint.h>

#define NB 4096
#define NC 100
#define NROWS (NB*NC)        // 409600
#define NTILES (NROWS/64)    // 6400
#define GRID_F 768
#define LH 200
#define LW 50

typedef short v8s __attribute__((ext_vector_type(8)));
typedef float v4f __attribute__((ext_vector_type(4)));
typedef float v2f __attribute__((ext_vector_type(2)));
typedef uint32_t v4u __attribute__((ext_vector_type(4)));

__device__ __forceinline__ v4f mfma16(v8s a, v8s b, v4f c) {
  return __builtin_amdgcn_mfma_f32_16x16x32_bf16(a, b, c, 0, 0, 0);
}

// packed f32x2 -> bf16x2 (lo = first arg), RNE
__device__ __forceinline__ uint32_t pkbf(float lo, float hi) {
  uint32_t r;
  asm("v_cvt_pk_bf16_f32 %0, %1, %2" : "=v"(r) : "v"(lo), "v"(hi));
  return r;
}

__device__ __forceinline__ uint16_t bf16r(float f) {
  uint32_t u = __builtin_bit_cast(uint32_t, f);
  u = (u + 0x7fffu + ((u >> 16) & 1u)) >> 16;
  return (uint16_t)u;
}

__device__ __forceinline__ float flo(uint32_t u) { return __builtin_bit_cast(float, u << 16); }
__device__ __forceinline__ float fhi(uint32_t u) { return __builtin_bit_cast(float, u & 0xffff0000u); }

__device__ __forceinline__ int ntli(const int* p) { return __builtin_nontemporal_load(p); }
__device__ __forceinline__ float ntlf(const float* p) { return __builtin_nontemporal_load(p); }

// barrier that does NOT drain vmcnt: LDS-safe (lgkmcnt), global loads stay in flight
__device__ __forceinline__ void barx() {
  asm volatile("s_waitcnt lgkmcnt(0)" ::: "memory");
  __builtin_amdgcn_s_barrier();
  asm volatile("" ::: "memory");
}

// ---------------- workspace layout ----------------
// [0,256K) uvb bf16-paired | [256K,384K) frags | [384K,...) bf16 tables (greedy tiers)
#define OFF_UVB 0
#define OFF_FW  262144
#define OFF_TB  393216
#define ET_BYTES (34253*64)
#define EC_BYTES (10001*64)
#define EA_BYTES (5001*64)
#define EL_BYTES (28*64)
#define WS_ALL (OFF_TB + ET_BYTES + EC_BYTES + EA_BYTES + EL_BYTES)  // 3,547,328
#define WS_ET  (OFF_TB + ET_BYTES)                                   // 2,585,408
#define WS_CAL (OFF_TB + EC_BYTES + EA_BYTES + EL_BYTES)             // 1,355,136

#define FRAG_B1 0     // 2 frags (even/odd output cols)
#define FRAG_T0 2     // 32 frags: g = wv*8 + ch*4 + ks*2 + p   (k identity)
#define FRAG_T1 34    // 64 frags: g = wv*16 + ch*8 + ks*2 + p  (k pkbf-paired)
#define FRAG_T2 98    // 16 frags: g = gcol*4 + ks              (k pkbf-paired, n=gcol*16+lr)
#define NFRAGS 114

// ---------------- f32 -> bf16 table convert ----------------
__global__ void k_cvt1(const float* __restrict__ src, uint32_t* __restrict__ dst, int n8) {
  int i = blockIdx.x * 256 + threadIdx.x;
  if (i >= n8) return;
  const float* p = src + (size_t)i * 8;
  float4 a = *(const float4*)p;
  float4 b = *(const float4*)(p + 4);
  uint32_t* d = dst + (size_t)i * 4;
  d[0] = pkbf(a.x, a.y); d[1] = pkbf(a.z, a.w);
  d[2] = pkbf(b.x, b.y); d[3] = pkbf(b.z, b.w);
}

// ---------------- build weight B-fragments ----------------
__global__ void k_prep(const float* __restrict__ Wb1, const float* __restrict__ Wt0,
                       const float* __restrict__ Wt1, const float* __restrict__ Wt2,
                       uint16_t* __restrict__ fb) {
  int f = blockIdx.x;
  int t = threadIdx.x;
  uint16_t res[2];
  #pragma unroll
  for (int e2 = 0; e2 < 2; ++e2) {
    int e = t * 2 + e2;        // 0..511
    int l = e >> 3, i = e & 7;
    int lr = l & 15, lg = l >> 4;
    float v;
    if (f < FRAG_T0) {                       // Wb1: frag f holds output cols 2*lr+f
      v = Wb1[(lg * 8 + i) * 32 + 2 * lr + f];
    } else if (f < FRAG_T1) {                // Wt0 (k identity)
      int g = f - FRAG_T0;
      int wv = g >> 3, ch = (g >> 2) & 1, ks = (g >> 1) & 1, p = g & 1;
      int n = ch * 128 + wv * 32 + p * 16 + lr;
      int kl = ks * 32 + lg * 8 + i;
      v = Wt0[kl * 256 + n];
    } else if (f < FRAG_T2) {                // Wt1 (act1 pkbf-paired)
      int g = f - FRAG_T1;
      int wv = g >> 4, ch = (g >> 3) & 1, ks = (g >> 1) & 3, p = g & 1;
      int n = wv * 32 + p * 16 + lr;
      int kl = ks * 32 + lg * 8 + i;
      int ok = ch * 128 + (kl & ~31) + ((kl & 31) >> 1) + ((kl & 1) << 4);
      v = Wt1[ok * 128 + n];
    } else {                                 // Wt2 (act2 pkbf-paired)
      int g = f - FRAG_T2;
      int gc = g >> 2, ks = g & 3;
      int n = gc * 16 + lr;
      int kl = ks * 32 + lg * 8 + i;
      int ok = (kl & ~31) + ((kl & 31) >> 1) + ((kl & 1) << 4);
      v = Wt2[ok * 64 + n];
    }
    res[e2] = bf16r(v);
  }
  *(uint32_t*)(fb + (size_t)f * 512 + t * 2) = (uint32_t)res[0] | ((uint32_t)res[1] << 16);
}

// ---------------- user vector -> bf16-paired uvb ----------------
__global__ void k_user_bf(const int* __restrict__ hist, const int* __restrict__ wish,
                          const float* __restrict__ Eh, const float* __restrict__ Ew,
                          uint32_t* __restrict__ uvb) {
  int t = threadIdx.x;
  int d2 = t & 15;                    // dim pair (2*d2, 2*d2+1)
  int r = blockIdx.x * 16 + (t >> 4);
  const int* hr = hist + r * LH;
  float sl = 0.f, sh = 0.f;
  #pragma unroll 8
  for (int j = 0; j < LH; ++j) {
    v2f e = *(const v2f*)(Eh + ntli(hr + j) * 32 + 2 * d2);
    sl += e[0]; sh += e[1];
  }
  const int* wr = wish + r * LW;
  float wl = 0.f, wh = 0.f;
  #pragma unroll 5
  for (int j = 0; j < LW; ++j) {
    v2f e = *(const v2f*)(Ew + ntli(wr + j) * 32 + 2 * d2);
    wl += e[0]; wh += e[1];
  }
  uvb[r * 16 + d2] = pkbf(sl * (1.0f/LH) + wl * (1.0f/LW), sh * (1.0f/LH) + wh * (1.0f/LW));
}

// gather 2 dims (2*lr, 2*lr+1): compile-time bf16/f32 path
template<int BF>
__device__ __forceinline__ void g2t(const uint16_t* B, const float* F, int idx, int lr,
                                    float& a0, float& a1) {
  if constexpr (BF) {
    uint32_t g = *(const uint32_t*)((const char*)B + ((size_t)idx << 6) + (lr << 2));
    a0 = flo(g); a1 = fhi(g);
  } else {
    v2f e = *(const v2f*)(F + idx * 32 + 2 * lr);
    a0 = e[0]; a1 = e[1];
  }
}

// ---------------- fused item pipeline (5 barriers/tile) ----------------
#define SM_CONST 0       // 672 f32 = 2688 B
#define SM_X     2688    // [64][128B] = 8192
#define SM_H     10880   // [64][64B]  = 4096
#define SM_ACT1  14976   // [64][512B] = 32768 ; ACT2 aliases first 16384
#define SM_ACT2  14976   // [64][256B]
#define SM_IDX   47744   // 64 x 8 idx x 4B = 2048
#define SM_BYTES 49792
// cf: 0 bb1[32] | 32 bt0[256] | 288 bt1[128] | 416 bt2[64] | 480 bb0[32] | 512 Wb0[96] | 608 Wt3[64]

template<int TET, int TEC, int TEA, int TEL>
__global__ __launch_bounds__(256, 3)
void k_fused(const int* __restrict__ cand, const int* __restrict__ auth,
             const int* __restrict__ lang, const int* __restrict__ tags,
             const float* __restrict__ dense,
             const float* __restrict__ Ec, const float* __restrict__ Ea,
             const float* __restrict__ El, const float* __restrict__ Et,
             const uint16_t* __restrict__ EcB, const uint16_t* __restrict__ EaB,
             const uint16_t* __restrict__ ElB, const uint16_t* __restrict__ EtB,
             const float* __restrict__ Wb0, const float* __restrict__ bb0,
             const float* __restrict__ bb1, const float* __restrict__ bt0,
             const float* __restrict__ bt1, const float* __restrict__ bt2,
             const float* __restrict__ Wt3, const float* __restrict__ bt3,
             const uint32_t* __restrict__ uvb, const uint16_t* __restrict__ fw,
             float* __restrict__ out) {
  extern __shared__ char sm[];
  const char* fwp = (const char*)fw;
  float* cf = (float*)(sm + SM_CONST);
  const int t = threadIdx.x;
  const int l = t & 63, wv = t >> 6;
  const int lr = l & 15, lg = l >> 4;
  const int q = t & 3, rowl = t >> 2;

  // ---- stage constants (LDS) ----
  cf[32 + t] = bt0[t];
  if (t < 128) cf[288 + t] = bt1[t];
  if (t < 64)  { cf[416 + t] = bt2[t]; cf[608 + t] = Wt3[t]; }
  if (t < 32)  { cf[t] = bb1[t]; cf[480 + t] = bb0[t]; }
  if (t < 96)  cf[512 + t] = Wb0[t];
  const float bt3v = bt3[0];

  // loop-invariant b1 weight fragments (global, L2-hot)
  v8s wbl = *(const v8s*)(fwp + (size_t)(FRAG_B1 + 0) * 1024 + l * 16);
  v8s wbh = *(const v8s*)(fwp + (size_t)(FRAG_B1 + 1) * 1024 + l * 16);

  // ---- stream prefetch state (one tile lookahead, 9 regs) ----
  v4u u4;
  float d3x, d3y, d3z;
  int i2a, i2b;
  auto ld_tile = [&](int tl) {
    int rr0 = (tl << 6) + rowl;
    int b = rr0 / 100;
    u4 = *(const v4u*)(uvb + b * 16 + q * 4);
    d3x = ntlf(dense + rr0 * 3 + 0);
    d3y = ntlf(dense + rr0 * 3 + 1);
    d3z = ntlf(dense + rr0 * 3 + 2);
    int s0 = q * 2;
    i2a = (s0 == 0) ? ntli(cand + rr0) : (s0 == 2) ? ntli(lang + rr0)
        : (s0 == 4) ? ntli(tags + rr0 * 5 + 1) : ntli(tags + rr0 * 5 + 3);
    i2b = (s0 == 0) ? ntli(auth + rr0) : (s0 == 2) ? ntli(tags + rr0 * 5 + 0)
        : (s0 == 4) ? ntli(tags + rr0 * 5 + 2) : ntli(tags + rr0 * 5 + 4);
  };
  ld_tile(blockIdx.x);

  barx();   // constants staged

  for (int tile = blockIdx.x; tile < NTILES; tile += GRID_F) {
    const int r0 = tile << 6;

    // ---- P0: X u-part + IDX + bottom-MLP layer0 (h) ----
    {
      int xrb = SM_X + rowl * 128;
      int sw  = (rowl & 7) << 4;
      #pragma unroll
      for (int k2 = 0; k2 < 4; ++k2)
        *(uint32_t*)(sm + xrb + ((q * 16 + k2 * 4) ^ sw)) = u4[k2];
      *(int*)(sm + SM_IDX + rowl * 32 + q * 8)     = i2a;
      *(int*)(sm + SM_IDX + rowl * 32 + q * 8 + 4) = i2b;
      const float* bb0l = cf + 480;
      const float* w0a = cf + 512, *w0b = cf + 544, *w0c = cf + 576;
      int hrb = SM_H + rowl * 64;
      int sw3 = (rowl & 3) << 4;
      #pragma unroll
      for (int u2 = 0; u2 < 4; ++u2) {
        int e0 = q * 8 + u2 * 2, e1 = e0 + 1;
        float h0 = fmaxf(bb0l[e0] + d3x * w0a[e0] + d3y * w0b[e0] + d3z * w0c[e0], 0.f);
        float h1 = fmaxf(bb0l[e1] + d3x * w0a[e1] + d3y * w0b[e1] + d3z * w0c[e1], 0.f);
        *(uint32_t*)(sm + hrb + ((q * 16 + u2 * 4) ^ sw3)) = pkbf(h0, h1);
      }
    }
    barx();

    // ---- P1: b1 MFMA (d_vec) + inline gathers -> X i-part ----
    {
      int hrow = 16 * wv + lr;
      v8s ah = *(const v8s*)(sm + SM_H + hrow * 64 + ((lg * 16) ^ ((hrow & 3) << 4)));
      float b0v = cf[2 * lr], b1v = cf[2 * lr + 1];
      v4f dv0 = {b0v, b0v, b0v, b0v};
      v4f dv1 = {b1v, b1v, b1v, b1v};
      dv0 = mfma16(ah, wbl, dv0);   // i dims 2*lr
      dv1 = mfma16(ah, wbh, dv1);   // i dims 2*lr+1
      #pragma unroll
      for (int j = 0; j < 4; ++j) {
        int mrow = 16 * wv + lg * 4 + j;
        const int* ip = (const int*)(sm + SM_IDX + mrow * 32);
        int ic = ip[0], ia = ip[1], il = ip[2];
        int x0 = ip[3], x1 = ip[4], x2 = ip[5], x3 = ip[6], x4 = ip[7];
        float c0, c1, a0, a1, l0, l1, p0, p1, p2, p3, p4, p5, p6, p7, p8, p9;
        g2t<TEC>(EcB, Ec, ic, lr, c0, c1);
        g2t<TEA>(EaB, Ea, ia, lr, a0, a1);
        g2t<TEL>(ElB, El, il, lr, l0, l1);
        g2t<TET>(EtB, Et, x0, lr, p0, p1);
        g2t<TET>(EtB, Et, x1, lr, p2, p3);
        g2t<TET>(EtB, Et, x2, lr, p4, p5);
        g2t<TET>(EtB, Et, x3, lr, p6, p7);
        g2t<TET>(EtB, Et, x4, lr, p8, p9);
        float s0 = c0 + a0 + l0 + (p0 + p2 + p4 + p6 + p8) * 0.2f + dv0[j];
        float s1 = c1 + a1 + l1 + (p1 + p3 + p5 + p7 + p9) * 0.2f + dv1[j];
        *(uint32_t*)(sm + SM_X + mrow * 128 + ((64 + 4 * lr) ^ ((mrow & 7) << 4))) = pkbf(s0, s1);
      }
    }
    barx();

    // streams for t+1 issued here: in flight across barriers, consumed next P0
    if (tile + GRID_F < NTILES) ld_tile(tile + GRID_F);

    // ---- t0 (64->256): inline frags, both chunks, one barrier ----
    #pragma unroll
    for (int ch = 0; ch < 2; ++ch) {
      v4f a1[2][4];
      #pragma unroll
      for (int p = 0; p < 2; ++p) {
        float bv = cf[32 + ch * 128 + wv * 32 + p * 16 + lr];
        #pragma unroll
        for (int m = 0; m < 4; ++m) a1[p][m] = (v4f){bv, bv, bv, bv};
      }
      #pragma unroll
      for (int ks = 0; ks < 2; ++ks) {
        v8s f0 = *(const v8s*)(fwp + (size_t)(FRAG_T0 + wv * 8 + ch * 4 + ks * 2 + 0) * 1024 + l * 16);
        v8s f1 = *(const v8s*)(fwp + (size_t)(FRAG_T0 + wv * 8 + ch * 4 + ks * 2 + 1) * 1024 + l * 16);
        #pragma unroll
        for (int m = 0; m < 4; ++m) {
          v8s xa = *(const v8s*)(sm + SM_X + (m * 16 + lr) * 128 + ((ks * 64 + lg * 16) ^ ((lr & 7) << 4)));
          a1[0][m] = mfma16(xa, f0, a1[0][m]);
          a1[1][m] = mfma16(xa, f1, a1[1][m]);
        }
      }
      #pragma unroll
      for (int m = 0; m < 4; ++m) {
        #pragma unroll
        for (int j = 0; j < 4; ++j) {
          int row = m * 16 + lg * 4 + j;
          *(uint32_t*)(sm + SM_ACT1 + row * 512 + ((ch * 256 + wv * 64 + 4 * lr) ^ ((row & 7) << 4)))
            = pkbf(fmaxf(a1[0][m][j], 0.f), fmaxf(a1[1][m][j], 0.f));
        }
      }
    }
    barx();

    // ---- t1 (256->128): inline frags ----
    v4f acc2[2][4];
    #pragma unroll
    for (int p = 0; p < 2; ++p) {
      float bv = cf[288 + wv * 32 + p * 16 + lr];
      #pragma unroll
      for (int m = 0; m < 4; ++m) acc2[p][m] = (v4f){bv, bv, bv, bv};
    }
    #pragma unroll
    for (int ch = 0; ch < 2; ++ch) {
      #pragma unroll
      for (int ks = 0; ks < 4; ++ks) {
        v8s f0 = *(const v8s*)(fwp + (size_t)(FRAG_T1 + wv * 16 + ch * 8 + ks * 2 + 0) * 1024 + l * 16);
        v8s f1 = *(const v8s*)(fwp + (size_t)(FRAG_T1 + wv * 16 + ch * 8 + ks * 2 + 1) * 1024 + l * 16);
        #pragma unroll
        for (int m = 0; m < 4; ++m) {
          v8s aa = *(const v8s*)(sm + SM_ACT1 + (m * 16 + lr) * 512 + ((ch * 256 + ks * 64 + lg * 16) ^ ((lr & 7) << 4)));
          acc2[0][m] = mfma16(aa, f0, acc2[0][m]);
          acc2[1][m] = mfma16(aa, f1, acc2[1][m]);
        }
      }
    }
    barx();   // ACT1 dead

    // ---- act2 write (relu, paired) ----
    #pragma unroll
    for (int m = 0; m < 4; ++m) {
      #pragma unroll
      for (int j = 0; j < 4; ++j) {
        int row = m * 16 + lg * 4 + j;
        *(uint32_t*)(sm + SM_ACT2 + row * 256 + ((wv * 64 + 4 * lr) ^ ((row & 7) << 4)))
          = pkbf(fmaxf(acc2[0][m][j], 0.f), fmaxf(acc2[1][m][j], 0.f));
      }
    }
    barx();

    // ---- t2 (inline frags) + t3, no trailing barrier (disjoint from next P0) ----
    {
      int arow = 16 * wv + lr;
      float bv0 = cf[416 + lr],      bv1 = cf[416 + 16 + lr];
      float bv2 = cf[416 + 32 + lr], bv3 = cf[416 + 48 + lr];
      v4f a3[4] = {{bv0, bv0, bv0, bv0}, {bv1, bv1, bv1, bv1},
                   {bv2, bv2, bv2, bv2}, {bv3, bv3, bv3, bv3}};
      #pragma unroll
      for (int ks = 0; ks < 4; ++ks) {
        v8s aa = *(const v8s*)(sm + SM_ACT2 + arow * 256 + ((ks * 64 + lg * 16) ^ ((arow & 7) << 4)));
        #pragma unroll
        for (int g = 0; g < 4; ++g) {
          v8s fg = *(const v8s*)(fwp + (size_t)(FRAG_T2 + g * 4 + ks) * 1024 + l * 16);
          a3[g] = mfma16(aa, fg, a3[g]);
        }
      }
      float wr0 = cf[608 + lr],      wr1 = cf[608 + 16 + lr];
      float wr2 = cf[608 + 32 + lr], wr3 = cf[608 + 48 + lr];
      float o[4];
      #pragma unroll
      for (int j = 0; j < 4; ++j) {
        o[j] = fmaxf(a3[0][j], 0.f) * wr0 + fmaxf(a3[1][j], 0.f) * wr1
             + fmaxf(a3[2][j], 0.f) * wr2 + fmaxf(a3[3][j], 0.f) * wr3;
        o[j] += __shfl_xor(o[j], 1);
        o[j] += __shfl_xor(o[j], 2);
        o[j] += __shfl_xor(o[j], 4);
        o[j] += __shfl_xor(o[j], 8);
      }
      if (lr == 0) {
        float4 ov = {o[0] + bt3v, o[1] + bt3v, o[2] + bt3v, o[3] + bt3v};
        *(float4*)(out + r0 + wv * 16 + lg * 4) = ov;
      }
    }
  }
}

template<int TET, int TEC, int TEA, int TEL>
static void launch_fused(const int* cand, const int* auth, const int* lang, const int* tags,
                         const float* dense, const float* Ec, const float* Ea,
                         const float* El, const float* Et,
                         const uint16_t* EcB, const uint16_t* EaB,
                         const uint16_t* ElB, const uint16_t* EtB,
                         const float* Wb0, const float* bb0, const float* bb1,
                         const float* bt0, const float* bt1, const float* bt2,
                         const float* Wt3, const float* bt3,
                         const uint32_t* uvb, const uint16_t* fw, float* out,
                         hipStream_t stream) {
  auto kf = k_fused<TET, TEC, TEA, TEL>;
  (void)hipFuncSetAttribute((const void*)kf, hipFuncAttributeMaxDynamicSharedMemorySize, SM_BYTES);
  kf<<<GRID_F, 256, SM_BYTES, stream>>>(cand, auth, lang, tags, dense,
      Ec, Ea, El, Et, EcB, EaB, ElB, EtB, Wb0, bb0, bb1, bt0, bt1, bt2, Wt3, bt3,
      uvb, fw, out);
}

extern "C" void kernel_launch(void* const* d_in, const int* in_sizes, int n_in,
                              void* d_out, int out_size, void* d_ws, size_t ws_size,
                              hipStream_t stream) {
  const int*   hist  = (const int*)d_in[0];
  const int*   wish  = (const int*)d_in[1];
  const int*   cand  = (const int*)d_in[2];
  const int*   auth  = (const int*)d_in[3];
  const int*   lang  = (const int*)d_in[4];
  const int*   tags  = (const int*)d_in[5];
  const float* dense = (const float*)d_in[6];
  const float* Eh    = (const float*)d_in[7];
  const float* Ew    = (const float*)d_in[8];
  const float* Ec    = (const float*)d_in[9];
  const float* Ea    = (const float*)d_in[10];
  const float* El    = (const float*)d_in[11];
  const float* Et    = (const float*)d_in[12];
  const float* Wb0   = (const float*)d_in[13];
  const float* bb0   = (const float*)d_in[14];
  const float* Wb1   = (const float*)d_in[15];
  const float* bb1   = (const float*)d_in[16];
  const float* Wt0   = (const float*)d_in[17];
  const float* bt0   = (const float*)d_in[18];
  const float* Wt1   = (const float*)d_in[19];
  const float* bt1   = (const float*)d_in[20];
  const float* Wt2   = (const float*)d_in[21];
  const float* bt2   = (const float*)d_in[22];
  const float* Wt3   = (const float*)d_in[23];
  const float* bt3   = (const float*)d_in[24];
  char* wsb = (char*)d_ws;
  float* out = (float*)d_out;

  uint32_t* uvb = (uint32_t*)(wsb + OFF_UVB);
  uint16_t* fw  = (uint16_t*)(wsb + OFF_FW);

  k_prep<<<NFRAGS, 256, 0, stream>>>(Wb1, Wt0, Wt1, Wt2, fw);
  k_user_bf<<<NB / 16, 256, 0, stream>>>(hist, wish, Eh, Ew, uvb);

  if (ws_size >= (size_t)WS_ALL) {
    uint16_t* EtB = (uint16_t*)(wsb + OFF_TB);
    uint16_t* EcB = (uint16_t*)(wsb + OFF_TB + ET_BYTES);
    uint16_t* EaB = (uint16_t*)(wsb + OFF_TB + ET_BYTES + EC_BYTES);
    uint16_t* ElB = (uint16_t*)(wsb + OFF_TB + ET_BYTES + EC_BYTES + EA_BYTES);
    k_cvt1<<<(34253*4 + 255)/256, 256, 0, stream>>>(Et, (uint32_t*)EtB, 34253*4);
    k_cvt1<<<(10001*4 + 255)/256, 256, 0, stream>>>(Ec, (uint32_t*)EcB, 10001*4);
    k_cvt1<<<(5001*4 + 255)/256, 256, 0, stream>>>(Ea, (uint32_t*)EaB, 5001*4);
    k_cvt1<<<1, 256, 0, stream>>>(El, (uint32_t*)ElB, 28*4);
    launch_fused<1,1,1,1>(cand, auth, lang, tags, dense, Ec, Ea, El, Et,
                          EcB, EaB, ElB, EtB, Wb0, bb0, bb1, bt0, bt1, bt2, Wt3, bt3,
                          uvb, fw, out, stream);
  } else if (ws_size >= (size_t)WS_ET) {
    uint16_t* EtB = (uint16_t*)(wsb + OFF_TB);
    k_cvt1<<<(34253*4 + 255)/256, 256, 0, stream>>>(Et, (uint32_t*)EtB, 34253*4);
    launch_fused<1,0,0,0>(cand, auth, lang, tags, dense, Ec, Ea, El, Et,
                          nullptr, nullptr, nullptr, EtB, Wb0, bb0, bb1, bt0, bt1, bt2, Wt3, bt3,
                          uvb, fw, out, stream);
  } else if (ws_size >= (size_t)WS_CAL) {
    uint16_t* EcB = (uint16_t*)(wsb + OFF_TB);
    uint16_t* EaB = (uint16_t*)(wsb + OFF_TB + EC_BYTES);
    uint16_t* ElB = (uint16_t*)(wsb + OFF_TB + EC_BYTES + EA_BYTES);
    k_cvt1<<<(10001*4 + 255)/256, 256, 0, stream>>>(Ec, (uint32_t*)EcB, 10001*4);
    k_cvt1<<<(5001*4 + 255)/256, 256, 0, stream>>>(Ea, (uint32_t*)EaB, 5001*4);
    k_cvt1<<<1, 256, 0, stream>>>(El, (uint32_t*)ElB, 28*4);
    launch_fused<0,1,1,1>(cand, auth, lang, tags, dense, Ec, Ea, El, Et,
                          EcB, EaB, ElB, nullptr, Wb0, bb0, bb1, bt0, bt1, bt2, Wt3, bt3,
                          uvb, fw, out, stream);
  } else {
    launch_fused<0,0,0,0>(cand, auth, lang, tags, dense, Ec, Ea, El, Et,
                          nullptr, nullptr, nullptr, nullptr, Wb0, bb0, bb1, bt0, bt1, bt2, Wt3, bt3,
                          uvb, fw, out, stream);
  }
}

// Round 9
// 261.175 us; speedup vs baseline: 1.7822x; 1.1074x over previous
//
#include <hip/hip_runtime.h>
#include <hip/hip_bf16.h>
#include <stdint.h>

#define NB 4096
#define NC 100
#define NROWS (NB*NC)        // 409600
#define NTILES (NROWS/64)    // 6400
#define GRID_F 1024
#define LH 200
#define LW 50

typedef short v8s __attribute__((ext_vector_type(8)));
typedef float v4f __attribute__((ext_vector_type(4)));
typedef float v2f __attribute__((ext_vector_type(2)));
typedef uint32_t v4u __attribute__((ext_vector_type(4)));

__device__ __forceinline__ v4f mfma16(v8s a, v8s b, v4f c) {
  return __builtin_amdgcn_mfma_f32_16x16x32_bf16(a, b, c, 0, 0, 0);
}

// packed f32x2 -> bf16x2 (lo = first arg), RNE
__device__ __forceinline__ uint32_t pkbf(float lo, float hi) {
  uint32_t r;
  asm("v_cvt_pk_bf16_f32 %0, %1, %2" : "=v"(r) : "v"(lo), "v"(hi));
  return r;
}

__device__ __forceinline__ uint16_t bf16r(float f) {
  uint32_t u = __builtin_bit_cast(uint32_t, f);
  u = (u + 0x7fffu + ((u >> 16) & 1u)) >> 16;
  return (uint16_t)u;
}

__device__ __forceinline__ float flo(uint32_t u) { return __builtin_bit_cast(float, u << 16); }
__device__ __forceinline__ float fhi(uint32_t u) { return __builtin_bit_cast(float, u & 0xffff0000u); }

__device__ __forceinline__ int ntli(const int* p) { return __builtin_nontemporal_load(p); }
__device__ __forceinline__ float ntlf(const float* p) { return __builtin_nontemporal_load(p); }

// barrier that does NOT drain vmcnt: LDS-safe (lgkmcnt), global loads stay in flight
__device__ __forceinline__ void barx() {
  asm volatile("s_waitcnt lgkmcnt(0)" ::: "memory");
  __builtin_amdgcn_s_barrier();
  asm volatile("" ::: "memory");
}

// ---------------- workspace layout ----------------
// [0,256K) uvb bf16-paired | [256K,379K) frags | [384K,...) bf16 tables (greedy tiers)
#define OFF_UVB 0
#define OFF_FW  262144
#define OFF_TB  393216
#define ET_BYTES (34253*64)
#define EC_BYTES (10001*64)
#define EA_BYTES (5001*64)
#define EL_BYTES (28*64)
#define WS_ALL (OFF_TB + ET_BYTES + EC_BYTES + EA_BYTES + EL_BYTES)  // 3,547,328
#define WS_ET  (OFF_TB + ET_BYTES)                                   // 2,585,408
#define WS_CAL (OFF_TB + EC_BYTES + EA_BYTES + EL_BYTES)             // 1,355,136
#define WS_AL  (OFF_TB + EA_BYTES + EL_BYTES)                        //   715,072

#define FRAG_B1 0     // 2 frags (even/odd output cols)
#define FRAG_T0 2     // 32 frags: g = wv*8 + ch*4 + ks*2 + p   (k identity)
#define FRAG_T1 34    // 64 frags: g = wv*16 + ch*8 + ks*2 + p  (k pkbf-paired)
#define FRAG_T2 98    // 16 frags: g = gcol*4 + ks              (k pkbf-paired, n=gcol*16+lr)
#define NFRAGS 114

// ---------------- f32 -> bf16 table convert ----------------
__global__ void k_cvt1(const float* __restrict__ src, uint32_t* __restrict__ dst, int n8) {
  int i = blockIdx.x * 256 + threadIdx.x;
  if (i >= n8) return;
  const float* p = src + (size_t)i * 8;
  float4 a = *(const float4*)p;
  float4 b = *(const float4*)(p + 4);
  uint32_t* d = dst + (size_t)i * 4;
  d[0] = pkbf(a.x, a.y); d[1] = pkbf(a.z, a.w);
  d[2] = pkbf(b.x, b.y); d[3] = pkbf(b.z, b.w);
}

// ---------------- build weight B-fragments ----------------
__global__ void k_prep(const float* __restrict__ Wb1, const float* __restrict__ Wt0,
                       const float* __restrict__ Wt1, const float* __restrict__ Wt2,
                       uint16_t* __restrict__ fb) {
  int f = blockIdx.x;
  int t = threadIdx.x;
  uint16_t res[2];
  #pragma unroll
  for (int e2 = 0; e2 < 2; ++e2) {
    int e = t * 2 + e2;        // 0..511
    int l = e >> 3, i = e & 7;
    int lr = l & 15, lg = l >> 4;
    float v;
    if (f < FRAG_T0) {                       // Wb1: frag f holds output cols 2*lr+f
      v = Wb1[(lg * 8 + i) * 32 + 2 * lr + f];
    } else if (f < FRAG_T1) {                // Wt0 (k identity)
      int g = f - FRAG_T0;
      int wv = g >> 3, ch = (g >> 2) & 1, ks = (g >> 1) & 1, p = g & 1;
      int n = ch * 128 + wv * 32 + p * 16 + lr;
      int kl = ks * 32 + lg * 8 + i;
      v = Wt0[kl * 256 + n];
    } else if (f < FRAG_T2) {                // Wt1 (act1 pkbf-paired)
      int g = f - FRAG_T1;
      int wv = g >> 4, ch = (g >> 3) & 1, ks = (g >> 1) & 3, p = g & 1;
      int n = wv * 32 + p * 16 + lr;
      int kl = ks * 32 + lg * 8 + i;
      int ok = ch * 128 + (kl & ~31) + ((kl & 31) >> 1) + ((kl & 1) << 4);
      v = Wt1[ok * 128 + n];
    } else {                                 // Wt2 (act2 pkbf-paired)
      int g = f - FRAG_T2;
      int gc = g >> 2, ks = g & 3;
      int n = gc * 16 + lr;
      int kl = ks * 32 + lg * 8 + i;
      int ok = (kl & ~31) + ((kl & 31) >> 1) + ((kl & 1) << 4);
      v = Wt2[ok * 64 + n];
    }
    res[e2] = bf16r(v);
  }
  *(uint32_t*)(fb + (size_t)f * 512 + t * 2) = (uint32_t)res[0] | ((uint32_t)res[1] << 16);
}

// ---------------- user vector -> bf16-paired uvb ----------------
__global__ void k_user_bf(const int* __restrict__ hist, const int* __restrict__ wish,
                          const float* __restrict__ Eh, const float* __restrict__ Ew,
                          uint32_t* __restrict__ uvb) {
  int t = threadIdx.x;
  int d2 = t & 15;                    // dim pair (2*d2, 2*d2+1)
  int r = blockIdx.x * 16 + (t >> 4);
  const int* hr = hist + r * LH;
  float sl = 0.f, sh = 0.f;
  #pragma unroll 8
  for (int j = 0; j < LH; ++j) {
    v2f e = *(const v2f*)(Eh + ntli(hr + j) * 32 + 2 * d2);
    sl += e[0]; sh += e[1];
  }
  const int* wr = wish + r * LW;
  float wl = 0.f, wh = 0.f;
  #pragma unroll 5
  for (int j = 0; j < LW; ++j) {
    v2f e = *(const v2f*)(Ew + ntli(wr + j) * 32 + 2 * d2);
    wl += e[0]; wh += e[1];
  }
  uvb[r * 16 + d2] = pkbf(sl * (1.0f/LH) + wl * (1.0f/LW), sh * (1.0f/LH) + wh * (1.0f/LW));
}

// gather 2 dims (2*lr, 2*lr+1): compile-time bf16/f32 path
template<int BF>
__device__ __forceinline__ void g2t(const uint16_t* B, const float* F, int idx, int lr,
                                    float& a0, float& a1) {
  if constexpr (BF) {
    uint32_t g = *(const uint32_t*)((const char*)B + ((size_t)idx << 6) + (lr << 2));
    a0 = flo(g); a1 = fhi(g);
  } else {
    v2f e = *(const v2f*)(F + idx * 32 + 2 * lr);
    a0 = e[0]; a1 = e[1];
  }
}

// ---------------- fused item pipeline (7 barriers/tile, 4 blocks/CU) ----------------
#define SM_CONST 0       // 672 f32 = 2688 B
#define SM_X     2688    // [64][128B] = 8192
#define SM_ACT   10880   // [64][256B] = 16384 (act1 chunks, then act2)
#define SM_H     27264   // [64][64B]  = 4096
#define SM_IDX   31360   // 64 x 8 idx x 4B = 2048
#define SM_BYTES 33408
// cf: 0 bb1[32] | 32 bt0[256] | 288 bt1[128] | 416 bt2[64] | 480 bb0[32] | 512 Wb0[96] | 608 Wt3[64]

template<int TET, int TEC, int TEA, int TEL>
__global__ __launch_bounds__(256, 4)
void k_fused(const int* __restrict__ cand, const int* __restrict__ auth,
             const int* __restrict__ lang, const int* __restrict__ tags,
             const float* __restrict__ dense,
             const float* __restrict__ Ec, const float* __restrict__ Ea,
             const float* __restrict__ El, const float* __restrict__ Et,
             const uint16_t* __restrict__ EcB, const uint16_t* __restrict__ EaB,
             const uint16_t* __restrict__ ElB, const uint16_t* __restrict__ EtB,
             const float* __restrict__ Wb0, const float* __restrict__ bb0,
             const float* __restrict__ bb1, const float* __restrict__ bt0,
             const float* __restrict__ bt1, const float* __restrict__ bt2,
             const float* __restrict__ Wt3, const float* __restrict__ bt3,
             const uint32_t* __restrict__ uvb, const uint16_t* __restrict__ fw,
             float* __restrict__ out) {
  extern __shared__ char sm[];
  const char* fwp = (const char*)fw;
  float* cf = (float*)(sm + SM_CONST);
  const int t = threadIdx.x;
  const int l = t & 63, wv = t >> 6;
  const int lr = l & 15, lg = l >> 4;
  const int q = t & 3, rowl = t >> 2;

  // ---- stage constants (LDS) ----
  cf[32 + t] = bt0[t];
  if (t < 128) cf[288 + t] = bt1[t];
  if (t < 64)  { cf[416 + t] = bt2[t]; cf[608 + t] = Wt3[t]; }
  if (t < 32)  { cf[t] = bb1[t]; cf[480 + t] = bb0[t]; }
  if (t < 96)  cf[512 + t] = Wb0[t];
  const float bt3v = bt3[0];

  // loop-invariant b1 weight fragments (global, L2-hot)
  v8s wbl = *(const v8s*)(fwp + (size_t)(FRAG_B1 + 0) * 1024 + l * 16);
  v8s wbh = *(const v8s*)(fwp + (size_t)(FRAG_B1 + 1) * 1024 + l * 16);

  // ---- stream prefetch state (one tile lookahead, 9 regs) ----
  v4u u4;
  float d3x, d3y, d3z;
  int i2a, i2b;
  auto ld_tile = [&](int tl) {
    int rr0 = (tl << 6) + rowl;
    int b = rr0 / 100;
    u4 = *(const v4u*)(uvb + b * 16 + q * 4);
    d3x = ntlf(dense + rr0 * 3 + 0);
    d3y = ntlf(dense + rr0 * 3 + 1);
    d3z = ntlf(dense + rr0 * 3 + 2);
    int s0 = q * 2;
    i2a = (s0 == 0) ? ntli(cand + rr0) : (s0 == 2) ? ntli(lang + rr0)
        : (s0 == 4) ? ntli(tags + rr0 * 5 + 1) : ntli(tags + rr0 * 5 + 3);
    i2b = (s0 == 0) ? ntli(auth + rr0) : (s0 == 2) ? ntli(tags + rr0 * 5 + 0)
        : (s0 == 4) ? ntli(tags + rr0 * 5 + 2) : ntli(tags + rr0 * 5 + 4);
  };
  ld_tile(blockIdx.x);

  barx();   // constants staged

  for (int tile = blockIdx.x; tile < NTILES; tile += GRID_F) {
    const int r0 = tile << 6;

    // ---- P0: X u-part + IDX + bottom-MLP layer0 (h) ----
    {
      int xrb = SM_X + rowl * 128;
      int sw  = (rowl & 7) << 4;
      #pragma unroll
      for (int k2 = 0; k2 < 4; ++k2)
        *(uint32_t*)(sm + xrb + ((q * 16 + k2 * 4) ^ sw)) = u4[k2];
      *(int*)(sm + SM_IDX + rowl * 32 + q * 8)     = i2a;
      *(int*)(sm + SM_IDX + rowl * 32 + q * 8 + 4) = i2b;
      const float* bb0l = cf + 480;
      const float* w0a = cf + 512, *w0b = cf + 544, *w0c = cf + 576;
      int hrb = SM_H + rowl * 64;
      int sw3 = (rowl & 3) << 4;
      #pragma unroll
      for (int u2 = 0; u2 < 4; ++u2) {
        int e0 = q * 8 + u2 * 2, e1 = e0 + 1;
        float h0 = fmaxf(bb0l[e0] + d3x * w0a[e0] + d3y * w0b[e0] + d3z * w0c[e0], 0.f);
        float h1 = fmaxf(bb0l[e1] + d3x * w0a[e1] + d3y * w0b[e1] + d3z * w0c[e1], 0.f);
        *(uint32_t*)(sm + hrb + ((q * 16 + u2 * 4) ^ sw3)) = pkbf(h0, h1);
      }
    }
    barx();

    // ---- P1: b1 MFMA (d_vec) + inline gathers -> X i-part ----
    {
      int hrow = 16 * wv + lr;
      v8s ah = *(const v8s*)(sm + SM_H + hrow * 64 + ((lg * 16) ^ ((hrow & 3) << 4)));
      float b0v = cf[2 * lr], b1v = cf[2 * lr + 1];
      v4f dv0 = {b0v, b0v, b0v, b0v};
      v4f dv1 = {b1v, b1v, b1v, b1v};
      dv0 = mfma16(ah, wbl, dv0);   // i dims 2*lr
      dv1 = mfma16(ah, wbh, dv1);   // i dims 2*lr+1
      #pragma unroll
      for (int j = 0; j < 4; ++j) {
        int mrow = 16 * wv + lg * 4 + j;
        const int* ip = (const int*)(sm + SM_IDX + mrow * 32);
        int ic = ip[0], ia = ip[1], il = ip[2];
        int x0 = ip[3], x1 = ip[4], x2 = ip[5], x3 = ip[6], x4 = ip[7];
        float c0, c1, a0, a1, l0, l1, p0, p1, p2, p3, p4, p5, p6, p7, p8, p9;
        g2t<TEC>(EcB, Ec, ic, lr, c0, c1);
        g2t<TEA>(EaB, Ea, ia, lr, a0, a1);
        g2t<TEL>(ElB, El, il, lr, l0, l1);
        g2t<TET>(EtB, Et, x0, lr, p0, p1);
        g2t<TET>(EtB, Et, x1, lr, p2, p3);
        g2t<TET>(EtB, Et, x2, lr, p4, p5);
        g2t<TET>(EtB, Et, x3, lr, p6, p7);
        g2t<TET>(EtB, Et, x4, lr, p8, p9);
        float s0 = c0 + a0 + l0 + (p0 + p2 + p4 + p6 + p8) * 0.2f + dv0[j];
        float s1 = c1 + a1 + l1 + (p1 + p3 + p5 + p7 + p9) * 0.2f + dv1[j];
        *(uint32_t*)(sm + SM_X + mrow * 128 + ((64 + 4 * lr) ^ ((mrow & 7) << 4))) = pkbf(s0, s1);
      }
    }
    barx();

    // streams for t+1 issued here: in flight across barriers, consumed next P0
    if (tile + GRID_F < NTILES) ld_tile(tile + GRID_F);

    // ---- t0 (64->256) + t1 (256->128) in two 128-col chunks, shared 16KB ACT ----
    v4f acc2[2][4];
    #pragma unroll
    for (int ch = 0; ch < 2; ++ch) {
      v4f a1[2][4];
      #pragma unroll
      for (int p = 0; p < 2; ++p) {
        float bv = cf[32 + ch * 128 + wv * 32 + p * 16 + lr];
        #pragma unroll
        for (int m = 0; m < 4; ++m) a1[p][m] = (v4f){bv, bv, bv, bv};
      }
      #pragma unroll
      for (int ks = 0; ks < 2; ++ks) {
        v8s f0 = *(const v8s*)(fwp + (size_t)(FRAG_T0 + wv * 8 + ch * 4 + ks * 2 + 0) * 1024 + l * 16);
        v8s f1 = *(const v8s*)(fwp + (size_t)(FRAG_T0 + wv * 8 + ch * 4 + ks * 2 + 1) * 1024 + l * 16);
        #pragma unroll
        for (int m = 0; m < 4; ++m) {
          v8s xa = *(const v8s*)(sm + SM_X + (m * 16 + lr) * 128 + ((ks * 64 + lg * 16) ^ ((lr & 7) << 4)));
          a1[0][m] = mfma16(xa, f0, a1[0][m]);
          a1[1][m] = mfma16(xa, f1, a1[1][m]);
        }
      }
      #pragma unroll
      for (int m = 0; m < 4; ++m) {
        #pragma unroll
        for (int j = 0; j < 4; ++j) {
          int row = m * 16 + lg * 4 + j;
          *(uint32_t*)(sm + SM_ACT + row * 256 + ((wv * 64 + 4 * lr) ^ ((row & 7) << 4)))
            = pkbf(fmaxf(a1[0][m][j], 0.f), fmaxf(a1[1][m][j], 0.f));
        }
      }
      barx();
      if (ch == 0) {   // delayed init: don't keep acc2 live through t0ch0
        #pragma unroll
        for (int p = 0; p < 2; ++p) {
          float bv = cf[288 + wv * 32 + p * 16 + lr];
          #pragma unroll
          for (int m = 0; m < 4; ++m) acc2[p][m] = (v4f){bv, bv, bv, bv};
        }
      }
      #pragma unroll
      for (int ks = 0; ks < 4; ++ks) {
        v8s f0 = *(const v8s*)(fwp + (size_t)(FRAG_T1 + wv * 16 + ch * 8 + ks * 2 + 0) * 1024 + l * 16);
        v8s f1 = *(const v8s*)(fwp + (size_t)(FRAG_T1 + wv * 16 + ch * 8 + ks * 2 + 1) * 1024 + l * 16);
        #pragma unroll
        for (int m = 0; m < 4; ++m) {
          v8s aa = *(const v8s*)(sm + SM_ACT + (m * 16 + lr) * 256 + ((ks * 64 + lg * 16) ^ ((lr & 7) << 4)));
          acc2[0][m] = mfma16(aa, f0, acc2[0][m]);
          acc2[1][m] = mfma16(aa, f1, acc2[1][m]);
        }
      }
      barx();
    }

    // ---- act2 write (relu, paired) into same ACT buffer ----
    #pragma unroll
    for (int m = 0; m < 4; ++m) {
      #pragma unroll
      for (int j = 0; j < 4; ++j) {
        int row = m * 16 + lg * 4 + j;
        *(uint32_t*)(sm + SM_ACT + row * 256 + ((wv * 64 + 4 * lr) ^ ((row & 7) << 4)))
          = pkbf(fmaxf(acc2[0][m][j], 0.f), fmaxf(acc2[1][m][j], 0.f));
      }
    }
    barx();

    // ---- t2 (inline frags) + t3 fused, no trailing barrier ----
    // next P0 writes X/H/IDX, all disjoint from ACT read here; ACT next written
    // at t0ch0 which is separated by P0-bar + P1-bar.
    {
      int arow = 16 * wv + lr;
      float bv0 = cf[416 + lr],      bv1 = cf[416 + 16 + lr];
      float bv2 = cf[416 + 32 + lr], bv3 = cf[416 + 48 + lr];
      v4f a3[4] = {{bv0, bv0, bv0, bv0}, {bv1, bv1, bv1, bv1},
                   {bv2, bv2, bv2, bv2}, {bv3, bv3, bv3, bv3}};
      #pragma unroll
      for (int ks = 0; ks < 4; ++ks) {
        v8s aa = *(const v8s*)(sm + SM_ACT + arow * 256 + ((ks * 64 + lg * 16) ^ ((arow & 7) << 4)));
        #pragma unroll
        for (int g = 0; g < 4; ++g) {
          v8s fg = *(const v8s*)(fwp + (size_t)(FRAG_T2 + g * 4 + ks) * 1024 + l * 16);
          a3[g] = mfma16(aa, fg, a3[g]);
        }
      }
      float wr0 = cf[608 + lr],      wr1 = cf[608 + 16 + lr];
      float wr2 = cf[608 + 32 + lr], wr3 = cf[608 + 48 + lr];
      float o[4];
      #pragma unroll
      for (int j = 0; j < 4; ++j) {
        o[j] = fmaxf(a3[0][j], 0.f) * wr0 + fmaxf(a3[1][j], 0.f) * wr1
             + fmaxf(a3[2][j], 0.f) * wr2 + fmaxf(a3[3][j], 0.f) * wr3;
        o[j] += __shfl_xor(o[j], 1);
        o[j] += __shfl_xor(o[j], 2);
        o[j] += __shfl_xor(o[j], 4);
        o[j] += __shfl_xor(o[j], 8);
      }
      if (lr == 0) {
        float4 ov = {o[0] + bt3v, o[1] + bt3v, o[2] + bt3v, o[3] + bt3v};
        *(float4*)(out + r0 + wv * 16 + lg * 4) = ov;
      }
    }
  }
}

template<int TET, int TEC, int TEA, int TEL>
static void launch_fused(const int* cand, const int* auth, const int* lang, const int* tags,
                         const float* dense, const float* Ec, const float* Ea,
                         const float* El, const float* Et,
                         const uint16_t* EcB, const uint16_t* EaB,
                         const uint16_t* ElB, const uint16_t* EtB,
                         const float* Wb0, const float* bb0, const float* bb1,
                         const float* bt0, const float* bt1, const float* bt2,
                         const float* Wt3, const float* bt3,
                         const uint32_t* uvb, const uint16_t* fw, float* out,
                         hipStream_t stream) {
  auto kf = k_fused<TET, TEC, TEA, TEL>;
  (void)hipFuncSetAttribute((const void*)kf, hipFuncAttributeMaxDynamicSharedMemorySize, SM_BYTES);
  kf<<<GRID_F, 256, SM_BYTES, stream>>>(cand, auth, lang, tags, dense,
      Ec, Ea, El, Et, EcB, EaB, ElB, EtB, Wb0, bb0, bb1, bt0, bt1, bt2, Wt3, bt3,
      uvb, fw, out);
}

extern "C" void kernel_launch(void* const* d_in, const int* in_sizes, int n_in,
                              void* d_out, int out_size, void* d_ws, size_t ws_size,
                              hipStream_t stream) {
  const int*   hist  = (const int*)d_in[0];
  const int*   wish  = (const int*)d_in[1];
  const int*   cand  = (const int*)d_in[2];
  const int*   auth  = (const int*)d_in[3];
  const int*   lang  = (const int*)d_in[4];
  const int*   tags  = (const int*)d_in[5];
  const float* dense = (const float*)d_in[6];
  const float* Eh    = (const float*)d_in[7];
  const float* Ew    = (const float*)d_in[8];
  const float* Ec    = (const float*)d_in[9];
  const float* Ea    = (const float*)d_in[10];
  const float* El    = (const float*)d_in[11];
  const float* Et    = (const float*)d_in[12];
  const float* Wb0   = (const float*)d_in[13];
  const float* bb0   = (const float*)d_in[14];
  const float* Wb1   = (const float*)d_in[15];
  const float* bb1   = (const float*)d_in[16];
  const float* Wt0   = (const float*)d_in[17];
  const float* bt0   = (const float*)d_in[18];
  const float* Wt1   = (const float*)d_in[19];
  const float* bt1   = (const float*)d_in[20];
  const float* Wt2   = (const float*)d_in[21];
  const float* bt2   = (const float*)d_in[22];
  const float* Wt3   = (const float*)d_in[23];
  const float* bt3   = (const float*)d_in[24];
  char* wsb = (char*)d_ws;
  float* out = (float*)d_out;

  uint32_t* uvb = (uint32_t*)(wsb + OFF_UVB);
  uint16_t* fw  = (uint16_t*)(wsb + OFF_FW);

  k_prep<<<NFRAGS, 256, 0, stream>>>(Wb1, Wt0, Wt1, Wt2, fw);
  k_user_bf<<<NB / 16, 256, 0, stream>>>(hist, wish, Eh, Ew, uvb);

  if (ws_size >= (size_t)WS_ALL) {
    uint16_t* EtB = (uint16_t*)(wsb + OFF_TB);
    uint16_t* EcB = (uint16_t*)(wsb + OFF_TB + ET_BYTES);
    uint16_t* EaB = (uint16_t*)(wsb + OFF_TB + ET_BYTES + EC_BYTES);
    uint16_t* ElB = (uint16_t*)(wsb + OFF_TB + ET_BYTES + EC_BYTES + EA_BYTES);
    k_cvt1<<<(34253*4 + 255)/256, 256, 0, stream>>>(Et, (uint32_t*)EtB, 34253*4);
    k_cvt1<<<(10001*4 + 255)/256, 256, 0, stream>>>(Ec, (uint32_t*)EcB, 10001*4);
    k_cvt1<<<(5001*4 + 255)/256, 256, 0, stream>>>(Ea, (uint32_t*)EaB, 5001*4);
    k_cvt1<<<1, 256, 0, stream>>>(El, (uint32_t*)ElB, 28*4);
    launch_fused<1,1,1,1>(cand, auth, lang, tags, dense, Ec, Ea, El, Et,
                          EcB, EaB, ElB, EtB, Wb0, bb0, bb1, bt0, bt1, bt2, Wt3, bt3,
                          uvb, fw, out, stream);
  } else if (ws_size >= (size_t)WS_ET) {
    uint16_t* EtB = (uint16_t*)(wsb + OFF_TB);
    k_cvt1<<<(34253*4 + 255)/256, 256, 0, stream>>>(Et, (uint32_t*)EtB, 34253*4);
    launch_fused<1,0,0,0>(cand, auth, lang, tags, dense, Ec, Ea, El, Et,
                          nullptr, nullptr, nullptr, EtB, Wb0, bb0, bb1, bt0, bt1, bt2, Wt3, bt3,
                          uvb, fw, out, stream);
  } else if (ws_size >= (size_t)WS_CAL) {
    uint16_t* EcB = (uint16_t*)(wsb + OFF_TB);
    uint16_t* EaB = (uint16_t*)(wsb + OFF_TB + EC_BYTES);
    uint16_t* ElB = (uint16_t*)(wsb + OFF_TB + EC_BYTES + EA_BYTES);
    k_cvt1<<<(10001*4 + 255)/256, 256, 0, stream>>>(Ec, (uint32_t*)EcB, 10001*4);
    k_cvt1<<<(5001*4 + 255)/256, 256, 0, stream>>>(Ea, (uint32_t*)EaB, 5001*4);
    k_cvt1<<<1, 256, 0, stream>>>(El, (uint32_t*)ElB, 28*4);
    launch_fused<0,1,1,1>(cand, auth, lang, tags, dense, Ec, Ea, El, Et,
                          EcB, EaB, ElB, nullptr, Wb0, bb0, bb1, bt0, bt1, bt2, Wt3, bt3,
                          uvb, fw, out, stream);
  } else if (ws_size >= (size_t)WS_AL) {
    uint16_t* EaB = (uint16_t*)(wsb + OFF_TB);
    uint16_t* ElB = (uint16_t*)(wsb + OFF_TB + EA_BYTES);
    k_cvt1<<<(5001*4 + 255)/256, 256, 0, stream>>>(Ea, (uint32_t*)EaB, 5001*4);
    k_cvt1<<<1, 256, 0, stream>>>(El, (uint32_t*)ElB, 28*4);
    launch_fused<0,0,1,1>(cand, auth, lang, tags, dense, Ec, Ea, El, Et,
                          nullptr, EaB, ElB, nullptr, Wb0, bb0, bb1, bt0, bt1, bt2, Wt3, bt3,
                          uvb, fw, out, stream);
  } else {
    launch_fused<0,0,0,0>(cand, auth, lang, tags, dense, Ec, Ea, El, Et,
                          nullptr, nullptr, nullptr, nullptr, Wb0, bb0, bb1, bt0, bt1, bt2, Wt3, bt3,
                          uvb, fw, out, stream);
  }
}